// Round 2
// baseline (611.939 us; speedup 1.0000x reference)
//
#include <hip/hip_runtime.h>
#include <math.h>

#define TB 256
#define SCAN_ELEMS 8
#define SCAN_CHUNK (TB * SCAN_ELEMS)
#define LQ 40
#define LH 150

// ---------------- CSR build ----------------
// NOTE: harness delivers integer inputs as int32 (edge_index is int32 here).

__global__ void k_hist(const int* __restrict__ ei, int E, int* __restrict__ cnt) {
    int e = blockIdx.x * blockDim.x + threadIdx.x;
    if (e < E) atomicAdd(&cnt[ei[E + e]], 1);
}

__global__ void k_scan1(const int* __restrict__ cnt, int n, int* __restrict__ excl,
                        int* __restrict__ blksum) {
    __shared__ int sh[TB];
    int t = threadIdx.x;
    int base = blockIdx.x * SCAN_CHUNK + t * SCAN_ELEMS;
    int v[SCAN_ELEMS];
    int tot = 0;
    #pragma unroll
    for (int i = 0; i < SCAN_ELEMS; i++) {
        int idx = base + i;
        int c = (idx < n) ? cnt[idx] : 0;
        v[i] = tot;
        tot += c;
    }
    sh[t] = tot;
    __syncthreads();
    for (int off = 1; off < TB; off <<= 1) {
        int x = (t >= off) ? sh[t - off] : 0;
        __syncthreads();
        sh[t] += x;
        __syncthreads();
    }
    int excl_t = sh[t] - tot;
    if (t == TB - 1) blksum[blockIdx.x] = sh[t];
    #pragma unroll
    for (int i = 0; i < SCAN_ELEMS; i++) {
        int idx = base + i;
        if (idx < n) excl[idx] = excl_t + v[i];
    }
}

__global__ void k_scan2(int* __restrict__ blksum, int nb) {
    __shared__ int sh[TB];
    int t = threadIdx.x;
    int val = (t < nb) ? blksum[t] : 0;
    sh[t] = val;
    __syncthreads();
    for (int off = 1; off < TB; off <<= 1) {
        int x = (t >= off) ? sh[t - off] : 0;
        __syncthreads();
        sh[t] += x;
        __syncthreads();
    }
    if (t < nb) blksum[t] = sh[t] - val;  // exclusive
}

__global__ void k_scan3(int* __restrict__ rowptr, const int* __restrict__ blkoff, int n, int E) {
    int i = blockIdx.x * blockDim.x + threadIdx.x;
    if (i < n) rowptr[i] += blkoff[i / SCAN_CHUNK];
    if (i == 0) rowptr[n] = E;
}

__global__ void k_dinv(const int* __restrict__ rowptr, int n, float* __restrict__ dinv,
                       int* __restrict__ head) {
    int i = blockIdx.x * blockDim.x + threadIdx.x;
    if (i < n) {
        int b0 = rowptr[i], b1 = rowptr[i + 1];
        head[i] = b0;
        dinv[i] = 1.0f / sqrtf((float)(b1 - b0 + 1));
    }
}

__global__ void k_scatter(const int* __restrict__ ei, int E, int* __restrict__ head,
                          int* __restrict__ srcs) {
    int e = blockIdx.x * blockDim.x + threadIdx.x;
    if (e < E) {
        int d = ei[E + e];
        int p = atomicAdd(&head[d], 1);
        srcs[p] = ei[e];
    }
}

// ---------------- weight precompute: g = Wh @ Wr[2:], c_h = bh . Wr[2:] ----------------

__global__ void k_wprep(const float* __restrict__ Wh, const float* __restrict__ bh,
                        const float* __restrict__ Wr, float* __restrict__ gbuf) {
    int t = threadIdx.x;
    if (t < 4) {
        float s = 0.f;
        for (int m = 0; m < LH; m++) s += Wh[t * LH + m] * Wr[2 + m];
        gbuf[t] = s;
    } else if (t == 4) {
        float s = 0.f;
        for (int m = 0; m < LH; m++) s += bh[m] * Wr[2 + m];
        gbuf[4] = s;
    }
}

// ---------------- node passes ----------------

__global__ void k_prep_x(const float* __restrict__ x, const float* __restrict__ dinv, int n,
                         float4* __restrict__ xd) {
    int i = blockIdx.x * blockDim.x + threadIdx.x;
    if (i < n) {
        float4 xv = ((const float4*)x)[i];
        float di = dinv[i];
        xd[i] = make_float4(xv.x * di, xv.y * di, xv.z * di, xv.w * di);
    }
}

// A1 = P(x); s1d = (A1.g + c_h) * dinv
__global__ void k_aggA1(const int* __restrict__ rowptr, const int* __restrict__ srcs,
                        const float4* __restrict__ xd, const float* __restrict__ dinv,
                        const float* __restrict__ gbuf, int n, float4* __restrict__ A1,
                        float* __restrict__ s1d) {
    int i = blockIdx.x * blockDim.x + threadIdx.x;
    if (i >= n) return;
    int b0 = rowptr[i], b1 = rowptr[i + 1];
    float4 a = xd[i];  // self term (pre-scaled)
    for (int e = b0; e < b1; e++) {
        float4 s = xd[srcs[e]];
        a.x += s.x; a.y += s.y; a.z += s.z; a.w += s.w;
    }
    float di = dinv[i];
    a.x *= di; a.y *= di; a.z *= di; a.w *= di;
    A1[i] = a;
    float s1 = a.x * gbuf[0] + a.y * gbuf[1] + a.z * gbuf[2] + a.w * gbuf[3] + gbuf[4];
    s1d[i] = s1 * di;
}

// r = A1.xy @ Wr[0:2] + P(s1) + br ; store rd = r * dinv
__global__ void k_aggR(const int* __restrict__ rowptr, const int* __restrict__ srcs,
                       const float* __restrict__ s1d, const float* __restrict__ dinv,
                       const float4* __restrict__ A1, const float* __restrict__ Wr,
                       const float* __restrict__ br, int n, float* __restrict__ rd) {
    int i = blockIdx.x * blockDim.x + threadIdx.x;
    if (i >= n) return;
    int b0 = rowptr[i], b1 = rowptr[i + 1];
    float acc = s1d[i];
    for (int e = b0; e < b1; e++) acc += s1d[srcs[e]];
    float Ps1 = acc * dinv[i];
    float4 a = A1[i];
    float r = a.x * Wr[0] + a.y * Wr[1] + Ps1 + br[0];
    rd[i] = r * dinv[i];
}

// Pr = P(r); iteration 1 (v=0): v1 = max_j qbase_j ; store vd0 = v1 * dinv
__global__ void k_aggPr(const int* __restrict__ rowptr, const int* __restrict__ srcs,
                        const float* __restrict__ rd, const float* __restrict__ dinv,
                        const float4* __restrict__ A1, const float* __restrict__ Wq,
                        const float* __restrict__ bq, int n, float* __restrict__ Pr,
                        float* __restrict__ vd0) {
    int i = blockIdx.x * blockDim.x + threadIdx.x;
    if (i >= n) return;
    int b0 = rowptr[i], b1 = rowptr[i + 1];
    float acc = rd[i];
    for (int e = b0; e < b1; e++) acc += rd[srcs[e]];
    float pr = acc * dinv[i];
    Pr[i] = pr;
    float4 a = A1[i];
    float m = -1e30f;
    for (int j = 0; j < LQ; j++) {
        float q = a.x * Wq[j] + a.y * Wq[LQ + j] + pr * Wq[2 * LQ + j] + bq[j];
        m = fmaxf(m, q);
    }
    vd0[i] = m * dinv[i];
}

// one value iteration: Pv = P(v); v' = max_j (qbase_j + Pv*Wq[3,j])
__global__ void k_iter(const int* __restrict__ rowptr, const int* __restrict__ srcs,
                       const float* __restrict__ vdin, const float* __restrict__ dinv,
                       const float4* __restrict__ A1, const float* __restrict__ Pr,
                       const float* __restrict__ Wq, const float* __restrict__ bq, int n,
                       float* __restrict__ vdout) {
    int i = blockIdx.x * blockDim.x + threadIdx.x;
    if (i >= n) return;
    int b0 = rowptr[i], b1 = rowptr[i + 1];
    float acc = vdin[i];
    for (int e = b0; e < b1; e++) acc += vdin[srcs[e]];
    float pv = acc * dinv[i];
    float4 a = A1[i];
    float pr = Pr[i];
    float m = -1e30f;
    for (int j = 0; j < LQ; j++) {
        float q = a.x * Wq[j] + a.y * Wq[LQ + j] + pr * Wq[2 * LQ + j] + pv * Wq[3 * LQ + j] + bq[j];
        m = fmaxf(m, q);
    }
    vdout[i] = m * dinv[i];
}

// final q, then t = q @ Wpi[2:42] (4 vals), store td = t * dinv
__global__ void k_final(const int* __restrict__ rowptr, const int* __restrict__ srcs,
                        const float* __restrict__ vdin, const float* __restrict__ dinv,
                        const float4* __restrict__ A1, const float* __restrict__ Pr,
                        const float* __restrict__ Wq, const float* __restrict__ bq,
                        const float* __restrict__ Wpi, int n, float4* __restrict__ td) {
    int i = blockIdx.x * blockDim.x + threadIdx.x;
    if (i >= n) return;
    int b0 = rowptr[i], b1 = rowptr[i + 1];
    float acc = vdin[i];
    for (int e = b0; e < b1; e++) acc += vdin[srcs[e]];
    float pv = acc * dinv[i];
    float4 a = A1[i];
    float pr = Pr[i];
    float t0 = 0.f, t1 = 0.f, t2 = 0.f, t3 = 0.f;
    for (int j = 0; j < LQ; j++) {
        float q = a.x * Wq[j] + a.y * Wq[LQ + j] + pr * Wq[2 * LQ + j] + pv * Wq[3 * LQ + j] + bq[j];
        const float* wp = &Wpi[(2 + j) * 4];
        t0 += q * wp[0];
        t1 += q * wp[1];
        t2 += q * wp[2];
        t3 += q * wp[3];
    }
    float di = dinv[i];
    td[i] = make_float4(t0 * di, t1 * di, t2 * di, t3 * di);
}

// logits = A1.xy @ Wpi[0:2] + P(t) + bpi ; probs = softmax(logits)
__global__ void k_logits(const int* __restrict__ rowptr, const int* __restrict__ srcs,
                         const float4* __restrict__ td, const float* __restrict__ dinv,
                         const float4* __restrict__ A1, const float* __restrict__ Wpi,
                         const float* __restrict__ bpi, int n, float* __restrict__ out) {
    int i = blockIdx.x * blockDim.x + threadIdx.x;
    if (i >= n) return;
    int b0 = rowptr[i], b1 = rowptr[i + 1];
    float4 acc = td[i];
    for (int e = b0; e < b1; e++) {
        float4 s = td[srcs[e]];
        acc.x += s.x; acc.y += s.y; acc.z += s.z; acc.w += s.w;
    }
    float di = dinv[i];
    float4 a = A1[i];
    float l0 = a.x * Wpi[0] + a.y * Wpi[4] + acc.x * di + bpi[0];
    float l1 = a.x * Wpi[1] + a.y * Wpi[5] + acc.y * di + bpi[1];
    float l2 = a.x * Wpi[2] + a.y * Wpi[6] + acc.z * di + bpi[2];
    float l3 = a.x * Wpi[3] + a.y * Wpi[7] + acc.w * di + bpi[3];
    float mx = fmaxf(fmaxf(l0, l1), fmaxf(l2, l3));
    float e0 = expf(l0 - mx), e1 = expf(l1 - mx), e2 = expf(l2 - mx), e3 = expf(l3 - mx);
    float inv = 1.0f / (e0 + e1 + e2 + e3);
    size_t base = (size_t)i * 4;
    out[base + 0] = l0; out[base + 1] = l1; out[base + 2] = l2; out[base + 3] = l3;
    size_t pbase = (size_t)n * 4 + base;
    out[pbase + 0] = e0 * inv; out[pbase + 1] = e1 * inv;
    out[pbase + 2] = e2 * inv; out[pbase + 3] = e3 * inv;
}

extern "C" void kernel_launch(void* const* d_in, const int* in_sizes, int n_in,
                              void* d_out, int out_size, void* d_ws, size_t ws_size,
                              hipStream_t stream) {
    const float* x = (const float*)d_in[0];
    const int* ei = (const int*)d_in[1];   // int32! harness converts integer inputs
    const float* Wh = (const float*)d_in[2];
    const float* bh = (const float*)d_in[3];
    const float* Wr = (const float*)d_in[4];
    const float* br = (const float*)d_in[5];
    const float* Wq = (const float*)d_in[6];
    const float* bq = (const float*)d_in[7];
    const float* Wpi = (const float*)d_in[8];
    const float* bpi = (const float*)d_in[9];
    int n = in_sizes[0] / 4;
    int E = in_sizes[1] / 2;
    float* out = (float*)d_out;

    // workspace carve-up (256B aligned), with lifetime-based aliasing:
    //   bufF: cnt -> s1d -> vd0 ; bufG: head -> rd -> vd1 ; bufH: xd -> td
    char* w = (char*)d_ws;
    size_t off = 0;
    auto alloc = [&](size_t bytes) -> void* {
        void* p = w + off;
        off += (bytes + 255) & ~(size_t)255;
        return p;
    };
    int nblk1 = (n + SCAN_CHUNK - 1) / SCAN_CHUNK;
    int* rowptr = (int*)alloc((size_t)(n + 1) * 4);
    float* dinv = (float*)alloc((size_t)n * 4);
    float4* A1 = (float4*)alloc((size_t)n * 16);
    float* Pr = (float*)alloc((size_t)n * 4);
    void* bufF = alloc((size_t)n * 4);
    void* bufG = alloc((size_t)n * 4);
    void* bufH = alloc((size_t)n * 16);
    int* blksum = (int*)alloc((size_t)nblk1 * 4);
    float* gbuf = (float*)alloc(8 * 4);
    int* srcs = (int*)alloc((size_t)E * 4);

    int* cnt = (int*)bufF;
    float* s1d = (float*)bufF;
    float* vd0 = (float*)bufF;
    int* head = (int*)bufG;
    float* rd = (float*)bufG;
    float* vd1 = (float*)bufG;
    float4* xd = (float4*)bufH;
    float4* td = (float4*)bufH;

    hipMemsetAsync(cnt, 0, (size_t)n * 4, stream);

    int gE = (E + TB - 1) / TB;
    int gN = (n + TB - 1) / TB;

    k_hist<<<gE, TB, 0, stream>>>(ei, E, cnt);
    k_scan1<<<nblk1, TB, 0, stream>>>(cnt, n, rowptr, blksum);
    k_scan2<<<1, TB, 0, stream>>>(blksum, nblk1);
    k_scan3<<<gN, TB, 0, stream>>>(rowptr, blksum, n, E);
    k_dinv<<<gN, TB, 0, stream>>>(rowptr, n, dinv, head);
    k_scatter<<<gE, TB, 0, stream>>>(ei, E, head, srcs);
    k_wprep<<<1, TB, 0, stream>>>(Wh, bh, Wr, gbuf);
    k_prep_x<<<gN, TB, 0, stream>>>(x, dinv, n, xd);
    k_aggA1<<<gN, TB, 0, stream>>>(rowptr, srcs, xd, dinv, gbuf, n, A1, s1d);
    k_aggR<<<gN, TB, 0, stream>>>(rowptr, srcs, s1d, dinv, A1, Wr, br, n, rd);
    // Pr = P(r) and value-iteration 1 (v=0 -> Pv=0)
    k_aggPr<<<gN, TB, 0, stream>>>(rowptr, srcs, rd, dinv, A1, Wq, bq, n, Pr, vd0);
    // iterations 2..19 (K=20 -> reference loop body runs 19 times total)
    float* vin = vd0;
    float* vout = vd1;
    for (int it = 2; it <= 19; ++it) {
        k_iter<<<gN, TB, 0, stream>>>(rowptr, srcs, vin, dinv, A1, Pr, Wq, bq, n, vout);
        float* tmp = vin; vin = vout; vout = tmp;
    }
    // final q -> t = q @ Wpi[2:], then logits + softmax
    k_final<<<gN, TB, 0, stream>>>(rowptr, srcs, vin, dinv, A1, Pr, Wq, bq, Wpi, n, td);
    k_logits<<<gN, TB, 0, stream>>>(rowptr, srcs, td, dinv, A1, Wpi, bpi, n, out);
}

// Round 3
// 349.265 us; speedup vs baseline: 1.7521x; 1.7521x over previous
//
#include <hip/hip_runtime.h>
#include <math.h>

#define TB 256
#define PB 512
#define SCAN_ELEMS 8
#define SCAN_CHUNK (TB * SCAN_ELEMS)
#define P_CHUNK 8192
#define LQ 40
#define LH 150

// ================= scans (rowptr from cnt) =================

__global__ void k_scan1(const int* __restrict__ cnt, int n, int* __restrict__ excl,
                        int* __restrict__ blksum) {
    __shared__ int sh[TB];
    int t = threadIdx.x;
    int base = blockIdx.x * SCAN_CHUNK + t * SCAN_ELEMS;
    int v[SCAN_ELEMS];
    int tot = 0;
    #pragma unroll
    for (int i = 0; i < SCAN_ELEMS; i++) {
        int idx = base + i;
        int c = (idx < n) ? cnt[idx] : 0;
        v[i] = tot;
        tot += c;
    }
    sh[t] = tot;
    __syncthreads();
    for (int off = 1; off < TB; off <<= 1) {
        int x = (t >= off) ? sh[t - off] : 0;
        __syncthreads();
        sh[t] += x;
        __syncthreads();
    }
    int excl_t = sh[t] - tot;
    if (t == TB - 1) blksum[blockIdx.x] = sh[t];
    #pragma unroll
    for (int i = 0; i < SCAN_ELEMS; i++) {
        int idx = base + i;
        if (idx < n) excl[idx] = excl_t + v[i];
    }
}

__global__ void k_scan2(int* __restrict__ blksum, int nb) {
    __shared__ int sh[TB];
    int t = threadIdx.x;
    int val = (t < nb) ? blksum[t] : 0;
    sh[t] = val;
    __syncthreads();
    for (int off = 1; off < TB; off <<= 1) {
        int x = (t >= off) ? sh[t - off] : 0;
        __syncthreads();
        sh[t] += x;
        __syncthreads();
    }
    if (t < nb) blksum[t] = sh[t] - val;
}

__global__ void k_scan3(int* __restrict__ rowptr, const int* __restrict__ blkoff, int n, int E) {
    int i = blockIdx.x * blockDim.x + threadIdx.x;
    if (i < n) rowptr[i] += blkoff[i / SCAN_CHUNK];
    if (i == 0) rowptr[n] = E;
}

// ================= fast CSR build: bucketed 2-level partition =================
// bucket = dst >> SH, <=256 buckets; edge packed as (src<<SH)|(dst&mask)

__global__ void k_p1a(const int* __restrict__ eidst, int E, int SH, int* __restrict__ offs) {
    __shared__ int h[256];
    int t = threadIdx.x;
    for (int j = t; j < 256; j += blockDim.x) h[j] = 0;
    __syncthreads();
    int base = blockIdx.x * P_CHUNK;
    for (int k = t; k < P_CHUNK; k += blockDim.x) {
        int e = base + k;
        if (e < E) atomicAdd(&h[eidst[e] >> SH], 1);
    }
    __syncthreads();
    for (int j = t; j < 256; j += blockDim.x) offs[blockIdx.x * 256 + j] = h[j];
}

// per-bucket exclusive scan over blocks; btot[b] = bucket total
__global__ void k_pscanA(int* __restrict__ offs, int nblk, int* __restrict__ btot) {
    __shared__ int sh[256];
    int t = threadIdx.x, b = blockIdx.x;
    int v = (t < nblk) ? offs[t * 256 + b] : 0;
    sh[t] = v;
    __syncthreads();
    for (int off = 1; off < 256; off <<= 1) {
        int x = (t >= off) ? sh[t - off] : 0;
        __syncthreads();
        sh[t] += x;
        __syncthreads();
    }
    if (t < nblk) offs[t * 256 + b] = sh[t] - v;
    if (t == 255) btot[b] = sh[255];
}

__global__ void k_pscan2(const int* __restrict__ btot, int* __restrict__ bbase, int E) {
    __shared__ int sh[256];
    int t = threadIdx.x;
    int v = btot[t];
    sh[t] = v;
    __syncthreads();
    for (int off = 1; off < 256; off <<= 1) {
        int x = (t >= off) ? sh[t - off] : 0;
        __syncthreads();
        sh[t] += x;
        __syncthreads();
    }
    bbase[t] = sh[t] - v;
    if (t == 255) bbase[256] = sh[255];
}

__global__ void k_p1b(const int* __restrict__ ei, int E, int SH,
                      const int* __restrict__ offs, const int* __restrict__ bbase,
                      unsigned* __restrict__ ebuf) {
    __shared__ int head[256];
    int t = threadIdx.x;
    for (int j = t; j < 256; j += blockDim.x) head[j] = bbase[j] + offs[blockIdx.x * 256 + j];
    __syncthreads();
    int base = blockIdx.x * P_CHUNK;
    unsigned mask = (1u << SH) - 1u;
    for (int k = t; k < P_CHUNK; k += blockDim.x) {
        int e = base + k;
        if (e < E) {
            int d = ei[E + e];
            unsigned s = (unsigned)ei[e];
            int p = atomicAdd(&head[d >> SH], 1);
            ebuf[p] = (s << SH) | ((unsigned)d & mask);
        }
    }
}

// per-dst counts via LDS (replaces global-atomic k_hist)
__global__ void k_p2a(const unsigned* __restrict__ ebuf, const int* __restrict__ bbase,
                      int SH, int n, int* __restrict__ cnt) {
    __shared__ int c[1024];
    int b = blockIdx.x, t = threadIdx.x;
    int d0 = b << SH;
    int w = 1 << SH;
    int nd = n - d0; if (nd > w) nd = w;
    for (int j = t; j < nd; j += blockDim.x) c[j] = 0;
    __syncthreads();
    int e0 = bbase[b], e1 = bbase[b + 1];
    unsigned mask = (unsigned)(w - 1);
    for (int e = e0 + t; e < e1; e += blockDim.x) atomicAdd(&c[ebuf[e] & mask], 1);
    __syncthreads();
    for (int j = t; j < nd; j += blockDim.x) cnt[d0 + j] = c[j];
}

// final scatter: writes confined to this bucket's ~32KB srcs range (L2-resident)
__global__ void k_p2b(const unsigned* __restrict__ ebuf, const int* __restrict__ bbase,
                      const int* __restrict__ rowptr, int SH, int n, int* __restrict__ srcs) {
    __shared__ int head[1024];
    int b = blockIdx.x, t = threadIdx.x;
    int d0 = b << SH;
    int w = 1 << SH;
    int nd = n - d0; if (nd > w) nd = w;
    for (int j = t; j < nd; j += blockDim.x) head[j] = rowptr[d0 + j];
    __syncthreads();
    int e0 = bbase[b], e1 = bbase[b + 1];
    unsigned mask = (unsigned)(w - 1);
    for (int e = e0 + t; e < e1; e += blockDim.x) {
        unsigned pk = ebuf[e];
        int p = atomicAdd(&head[pk & mask], 1);
        srcs[p] = (int)(pk >> SH);
    }
}

// ================= legacy fallback (not used for this shape) =================

__global__ void k_hist(const int* __restrict__ ei, int E, int* __restrict__ cnt) {
    int e = blockIdx.x * blockDim.x + threadIdx.x;
    if (e < E) atomicAdd(&cnt[ei[E + e]], 1);
}
__global__ void k_headinit(const int* __restrict__ rowptr, int n, int* __restrict__ head) {
    int i = blockIdx.x * blockDim.x + threadIdx.x;
    if (i < n) head[i] = rowptr[i];
}
__global__ void k_scatter(const int* __restrict__ ei, int E, int* __restrict__ head,
                          int* __restrict__ srcs) {
    int e = blockIdx.x * blockDim.x + threadIdx.x;
    if (e < E) {
        int p = atomicAdd(&head[ei[E + e]], 1);
        srcs[p] = ei[e];
    }
}

// ================= weight precompute: g = Wh @ Wr[2:], c_h = bh . Wr[2:] =================

__global__ void k_wprep(const float* __restrict__ Wh, const float* __restrict__ bh,
                        const float* __restrict__ Wr, float* __restrict__ gbuf) {
    int t = threadIdx.x;
    if (t < 4) {
        float s = 0.f;
        for (int m = 0; m < LH; m++) s += Wh[t * LH + m] * Wr[2 + m];
        gbuf[t] = s;
    } else if (t == 4) {
        float s = 0.f;
        for (int m = 0; m < LH; m++) s += bh[m] * Wr[2 + m];
        gbuf[4] = s;
    }
}

// ================= node passes (all gathers 4-way unrolled for MLP) =================

__global__ void k_dinvprep(const int* __restrict__ rowptr, const float* __restrict__ x,
                           int n, float* __restrict__ dinv, float4* __restrict__ xd) {
    int i = blockIdx.x * blockDim.x + threadIdx.x;
    if (i >= n) return;
    int deg = rowptr[i + 1] - rowptr[i];
    float di = 1.0f / sqrtf((float)(deg + 1));
    dinv[i] = di;
    float4 xv = ((const float4*)x)[i];
    xd[i] = make_float4(xv.x * di, xv.y * di, xv.z * di, xv.w * di);
}

__global__ void k_aggA1(const int* __restrict__ rowptr, const int* __restrict__ srcs,
                        const float4* __restrict__ xd, const float* __restrict__ dinv,
                        const float* __restrict__ gbuf, int n,
                        float2* __restrict__ axy, float* __restrict__ s1d) {
    int i = blockIdx.x * blockDim.x + threadIdx.x;
    if (i >= n) return;
    int b0 = rowptr[i], b1 = rowptr[i + 1];
    float4 a0 = xd[i];
    float4 a1 = make_float4(0, 0, 0, 0), a2 = a1, a3 = a1;
    int e = b0;
    for (; e + 4 <= b1; e += 4) {
        int s0 = srcs[e], s1 = srcs[e + 1], s2 = srcs[e + 2], s3 = srcs[e + 3];
        float4 v0 = xd[s0], v1 = xd[s1], v2 = xd[s2], v3 = xd[s3];
        a0.x += v0.x; a0.y += v0.y; a0.z += v0.z; a0.w += v0.w;
        a1.x += v1.x; a1.y += v1.y; a1.z += v1.z; a1.w += v1.w;
        a2.x += v2.x; a2.y += v2.y; a2.z += v2.z; a2.w += v2.w;
        a3.x += v3.x; a3.y += v3.y; a3.z += v3.z; a3.w += v3.w;
    }
    for (; e < b1; ++e) {
        float4 v = xd[srcs[e]];
        a0.x += v.x; a0.y += v.y; a0.z += v.z; a0.w += v.w;
    }
    float di = dinv[i];
    float ax = ((a0.x + a1.x) + (a2.x + a3.x)) * di;
    float ay = ((a0.y + a1.y) + (a2.y + a3.y)) * di;
    float az = ((a0.z + a1.z) + (a2.z + a3.z)) * di;
    float aw = ((a0.w + a1.w) + (a2.w + a3.w)) * di;
    axy[i] = make_float2(ax, ay);
    float s1v = ax * gbuf[0] + ay * gbuf[1] + az * gbuf[2] + aw * gbuf[3] + gbuf[4];
    s1d[i] = s1v * di;
}

__global__ void k_aggR(const int* __restrict__ rowptr, const int* __restrict__ srcs,
                       const float* __restrict__ s1d, const float* __restrict__ dinv,
                       const float2* __restrict__ axy, const float* __restrict__ Wr,
                       const float* __restrict__ br, int n, float* __restrict__ rd) {
    int i = blockIdx.x * blockDim.x + threadIdx.x;
    if (i >= n) return;
    int b0 = rowptr[i], b1 = rowptr[i + 1];
    float c0 = s1d[i], c1 = 0.f, c2 = 0.f, c3 = 0.f;
    int e = b0;
    for (; e + 4 <= b1; e += 4) {
        int s0 = srcs[e], s1 = srcs[e + 1], s2 = srcs[e + 2], s3 = srcs[e + 3];
        c0 += s1d[s0]; c1 += s1d[s1]; c2 += s1d[s2]; c3 += s1d[s3];
    }
    for (; e < b1; ++e) c0 += s1d[srcs[e]];
    float di = dinv[i];
    float Ps1 = ((c0 + c1) + (c2 + c3)) * di;
    float2 a = axy[i];
    float r = a.x * Wr[0] + a.y * Wr[1] + Ps1 + br[0];
    rd[i] = r * di;
}

// Pr = P(r); first value-iteration (v=0 -> Pv=0); nd = (A1.x, A1.y, Pr, dinv)
__global__ void k_aggPr(const int* __restrict__ rowptr, const int* __restrict__ srcs,
                        const float* __restrict__ rd, const float* __restrict__ dinv,
                        const float2* __restrict__ axy, const float* __restrict__ Wq,
                        const float* __restrict__ bq, int n,
                        float4* __restrict__ nd, float* __restrict__ vd0) {
    int i = blockIdx.x * blockDim.x + threadIdx.x;
    if (i >= n) return;
    int b0 = rowptr[i], b1 = rowptr[i + 1];
    float c0 = rd[i], c1 = 0.f, c2 = 0.f, c3 = 0.f;
    int e = b0;
    for (; e + 4 <= b1; e += 4) {
        int s0 = srcs[e], s1 = srcs[e + 1], s2 = srcs[e + 2], s3 = srcs[e + 3];
        c0 += rd[s0]; c1 += rd[s1]; c2 += rd[s2]; c3 += rd[s3];
    }
    for (; e < b1; ++e) c0 += rd[srcs[e]];
    float di = dinv[i];
    float pr = ((c0 + c1) + (c2 + c3)) * di;
    float2 a = axy[i];
    nd[i] = make_float4(a.x, a.y, pr, di);
    float m = -1e30f;
    #pragma unroll
    for (int j = 0; j < LQ; j++) {
        float q = fmaf(a.x, Wq[j], fmaf(a.y, Wq[LQ + j], fmaf(pr, Wq[2 * LQ + j], bq[j])));
        m = fmaxf(m, q);
    }
    vd0[i] = m * di;
}

__global__ void k_iter(const int* __restrict__ rowptr, const int* __restrict__ srcs,
                       const float* __restrict__ vdin, const float4* __restrict__ nd,
                       const float* __restrict__ Wq, const float* __restrict__ bq, int n,
                       float* __restrict__ vdout) {
    int i = blockIdx.x * blockDim.x + threadIdx.x;
    if (i >= n) return;
    int b0 = rowptr[i], b1 = rowptr[i + 1];
    float c0 = vdin[i], c1 = 0.f, c2 = 0.f, c3 = 0.f;
    int e = b0;
    for (; e + 4 <= b1; e += 4) {
        int s0 = srcs[e], s1 = srcs[e + 1], s2 = srcs[e + 2], s3 = srcs[e + 3];
        c0 += vdin[s0]; c1 += vdin[s1]; c2 += vdin[s2]; c3 += vdin[s3];
    }
    for (; e < b1; ++e) c0 += vdin[srcs[e]];
    float4 c = nd[i];
    float pv = ((c0 + c1) + (c2 + c3)) * c.w;
    float m = -1e30f;
    #pragma unroll
    for (int j = 0; j < LQ; j++) {
        float q = fmaf(c.x, Wq[j],
                  fmaf(c.y, Wq[LQ + j],
                  fmaf(c.z, Wq[2 * LQ + j],
                  fmaf(pv, Wq[3 * LQ + j], bq[j]))));
        m = fmaxf(m, q);
    }
    vdout[i] = m * c.w;
}

__global__ void k_final(const int* __restrict__ rowptr, const int* __restrict__ srcs,
                        const float* __restrict__ vdin, const float4* __restrict__ nd,
                        const float* __restrict__ Wq, const float* __restrict__ bq,
                        const float* __restrict__ Wpi, int n, float4* __restrict__ td) {
    int i = blockIdx.x * blockDim.x + threadIdx.x;
    if (i >= n) return;
    int b0 = rowptr[i], b1 = rowptr[i + 1];
    float c0 = vdin[i], c1 = 0.f, c2 = 0.f, c3 = 0.f;
    int e = b0;
    for (; e + 4 <= b1; e += 4) {
        int s0 = srcs[e], s1 = srcs[e + 1], s2 = srcs[e + 2], s3 = srcs[e + 3];
        c0 += vdin[s0]; c1 += vdin[s1]; c2 += vdin[s2]; c3 += vdin[s3];
    }
    for (; e < b1; ++e) c0 += vdin[srcs[e]];
    float4 c = nd[i];
    float pv = ((c0 + c1) + (c2 + c3)) * c.w;
    float t0 = 0.f, t1 = 0.f, t2 = 0.f, t3 = 0.f;
    #pragma unroll
    for (int j = 0; j < LQ; j++) {
        float q = fmaf(c.x, Wq[j],
                  fmaf(c.y, Wq[LQ + j],
                  fmaf(c.z, Wq[2 * LQ + j],
                  fmaf(pv, Wq[3 * LQ + j], bq[j]))));
        const float* wp = &Wpi[(2 + j) * 4];
        t0 = fmaf(q, wp[0], t0);
        t1 = fmaf(q, wp[1], t1);
        t2 = fmaf(q, wp[2], t2);
        t3 = fmaf(q, wp[3], t3);
    }
    td[i] = make_float4(t0 * c.w, t1 * c.w, t2 * c.w, t3 * c.w);
}

__global__ void k_logits(const int* __restrict__ rowptr, const int* __restrict__ srcs,
                         const float4* __restrict__ td, const float4* __restrict__ nd,
                         const float* __restrict__ Wpi, const float* __restrict__ bpi,
                         int n, float* __restrict__ out) {
    int i = blockIdx.x * blockDim.x + threadIdx.x;
    if (i >= n) return;
    int b0 = rowptr[i], b1 = rowptr[i + 1];
    float4 a0 = td[i];
    float4 a1 = make_float4(0, 0, 0, 0), a2 = a1, a3 = a1;
    int e = b0;
    for (; e + 4 <= b1; e += 4) {
        int s0 = srcs[e], s1 = srcs[e + 1], s2 = srcs[e + 2], s3 = srcs[e + 3];
        float4 v0 = td[s0], v1 = td[s1], v2 = td[s2], v3 = td[s3];
        a0.x += v0.x; a0.y += v0.y; a0.z += v0.z; a0.w += v0.w;
        a1.x += v1.x; a1.y += v1.y; a1.z += v1.z; a1.w += v1.w;
        a2.x += v2.x; a2.y += v2.y; a2.z += v2.z; a2.w += v2.w;
        a3.x += v3.x; a3.y += v3.y; a3.z += v3.z; a3.w += v3.w;
    }
    for (; e < b1; ++e) {
        float4 v = td[srcs[e]];
        a0.x += v.x; a0.y += v.y; a0.z += v.z; a0.w += v.w;
    }
    float4 c = nd[i];
    float di = c.w;
    float l0 = c.x * Wpi[0] + c.y * Wpi[4] + ((a0.x + a1.x) + (a2.x + a3.x)) * di + bpi[0];
    float l1 = c.x * Wpi[1] + c.y * Wpi[5] + ((a0.y + a1.y) + (a2.y + a3.y)) * di + bpi[1];
    float l2 = c.x * Wpi[2] + c.y * Wpi[6] + ((a0.z + a1.z) + (a2.z + a3.z)) * di + bpi[2];
    float l3 = c.x * Wpi[3] + c.y * Wpi[7] + ((a0.w + a1.w) + (a2.w + a3.w)) * di + bpi[3];
    float mx = fmaxf(fmaxf(l0, l1), fmaxf(l2, l3));
    float e0 = expf(l0 - mx), e1 = expf(l1 - mx), e2 = expf(l2 - mx), e3 = expf(l3 - mx);
    float inv = 1.0f / (e0 + e1 + e2 + e3);
    size_t base = (size_t)i * 4;
    out[base + 0] = l0; out[base + 1] = l1; out[base + 2] = l2; out[base + 3] = l3;
    size_t pbase = (size_t)n * 4 + base;
    out[pbase + 0] = e0 * inv; out[pbase + 1] = e1 * inv;
    out[pbase + 2] = e2 * inv; out[pbase + 3] = e3 * inv;
}

extern "C" void kernel_launch(void* const* d_in, const int* in_sizes, int n_in,
                              void* d_out, int out_size, void* d_ws, size_t ws_size,
                              hipStream_t stream) {
    const float* x = (const float*)d_in[0];
    const int* ei = (const int*)d_in[1];   // int32: harness converts integer inputs
    const float* Wh = (const float*)d_in[2];
    const float* bh = (const float*)d_in[3];
    const float* Wr = (const float*)d_in[4];
    const float* br = (const float*)d_in[5];
    const float* Wq = (const float*)d_in[6];
    const float* bq = (const float*)d_in[7];
    const float* Wpi = (const float*)d_in[8];
    const float* bpi = (const float*)d_in[9];
    int n = in_sizes[0] / 4;
    int E = in_sizes[1] / 2;
    float* out = (float*)d_out;

    int SH = 0;
    while ((((n - 1) >> SH) + 1) > 256) SH++;
    int NB = ((n - 1) >> SH) + 1;
    int nblk2 = (E + P_CHUNK - 1) / P_CHUNK;
    bool fast = (SH <= 10) && (nblk2 <= 256) &&
                ((unsigned long long)n <= (1ull << (32 - SH)));

    char* w = (char*)d_ws;
    size_t off = 0;
    auto alloc = [&](size_t bytes) -> void* {
        void* p = w + off;
        off += (bytes + 255) & ~(size_t)255;
        return p;
    };
    auto AL = [](size_t b) { return (b + 255) & ~(size_t)255; };

    int nblk1 = (n + SCAN_CHUNK - 1) / SCAN_CHUNK;
    int* rowptr = (int*)alloc((size_t)(n + 1) * 4);
    int* srcs = (int*)alloc((size_t)E * 4);
    int* blksum = (int*)alloc((size_t)nblk1 * 4);
    int* btot = (int*)alloc(256 * 4);
    int* bbase = (int*)alloc(257 * 4);
    float* gbuf = (float*)alloc(8 * 4);
    int* offs = (int*)alloc((size_t)(fast ? nblk2 : 1) * 256 * 4);

    // BIG region: during CSR build holds [ebuf | cnt]; during passes overlaid by node arrays
    size_t o_dinv = 0;
    size_t o_xdtd = o_dinv + AL((size_t)n * 4);
    size_t o_axy  = o_xdtd + AL((size_t)n * 16);
    size_t o_s1   = o_axy + AL((size_t)n * 8);
    size_t o_rd   = o_s1 + AL((size_t)n * 4);
    size_t o_nd   = o_rd + AL((size_t)n * 4);
    size_t phaseB = o_nd + AL((size_t)n * 16);
    size_t o_cnt  = AL((size_t)E * 4);
    size_t buildB = o_cnt + AL((size_t)n * 4);
    size_t bigsz = phaseB > buildB ? phaseB : buildB;
    char* big = (char*)alloc(bigsz);

    unsigned* ebuf = (unsigned*)big;
    int* cnt = (int*)(big + o_cnt);
    float* dinv = (float*)(big + o_dinv);
    float4* xd = (float4*)(big + o_xdtd);
    float4* td = xd;                       // xd dead after aggA1
    float2* axy = (float2*)(big + o_axy);
    float* s1d = (float*)(big + o_s1);
    float* vd0 = s1d;                      // s1d dead after aggR
    float* rd = (float*)(big + o_rd);
    float* vd1 = rd;                       // rd dead after aggPr
    float4* nd = (float4*)(big + o_nd);
    int* head = (int*)nd;                  // legacy only; nd written later

    int gN = (n + TB - 1) / TB;
    int gE = (E + TB - 1) / TB;

    if (fast) {
        k_p1a<<<nblk2, PB, 0, stream>>>(ei + E, E, SH, offs);
        k_pscanA<<<256, 256, 0, stream>>>(offs, nblk2, btot);
        k_pscan2<<<1, 256, 0, stream>>>(btot, bbase, E);
        k_p1b<<<nblk2, PB, 0, stream>>>(ei, E, SH, offs, bbase, ebuf);
        k_p2a<<<NB, PB, 0, stream>>>(ebuf, bbase, SH, n, cnt);
        k_scan1<<<nblk1, TB, 0, stream>>>(cnt, n, rowptr, blksum);
        k_scan2<<<1, TB, 0, stream>>>(blksum, nblk1);
        k_scan3<<<gN, TB, 0, stream>>>(rowptr, blksum, n, E);
        k_p2b<<<NB, PB, 0, stream>>>(ebuf, bbase, rowptr, SH, n, srcs);
    } else {
        hipMemsetAsync(cnt, 0, (size_t)n * 4, stream);
        k_hist<<<gE, TB, 0, stream>>>(ei, E, cnt);
        k_scan1<<<nblk1, TB, 0, stream>>>(cnt, n, rowptr, blksum);
        k_scan2<<<1, TB, 0, stream>>>(blksum, nblk1);
        k_scan3<<<gN, TB, 0, stream>>>(rowptr, blksum, n, E);
        k_headinit<<<gN, TB, 0, stream>>>(rowptr, n, head);
        k_scatter<<<gE, TB, 0, stream>>>(ei, E, head, srcs);
    }

    k_dinvprep<<<gN, TB, 0, stream>>>(rowptr, x, n, dinv, xd);
    k_wprep<<<1, TB, 0, stream>>>(Wh, bh, Wr, gbuf);
    k_aggA1<<<gN, TB, 0, stream>>>(rowptr, srcs, xd, dinv, gbuf, n, axy, s1d);
    k_aggR<<<gN, TB, 0, stream>>>(rowptr, srcs, s1d, dinv, axy, Wr, br, n, rd);
    k_aggPr<<<gN, TB, 0, stream>>>(rowptr, srcs, rd, dinv, axy, Wq, bq, n, nd, vd0);

    float* vin = vd0;
    float* vout = vd1;
    for (int it = 2; it <= 19; ++it) {
        k_iter<<<gN, TB, 0, stream>>>(rowptr, srcs, vin, nd, Wq, bq, n, vout);
        float* tmp = vin; vin = vout; vout = tmp;
    }
    k_final<<<gN, TB, 0, stream>>>(rowptr, srcs, vin, nd, Wq, bq, Wpi, n, td);
    k_logits<<<gN, TB, 0, stream>>>(rowptr, srcs, td, nd, Wpi, bpi, n, out);
}

// Round 5
// 343.012 us; speedup vs baseline: 1.7840x; 1.0182x over previous
//
#include <hip/hip_runtime.h>
#include <hip/hip_cooperative_groups.h>
#include <math.h>

namespace cg = cooperative_groups;

#define TB 256
#define PB 512
#define SCAN_ELEMS 8
#define SCAN_CHUNK (TB * SCAN_ELEMS)
#define P_CHUNK 8192
#define LQ 40
#define LH 150
#define ECAP 12288
#define MTB 512

// ================= scans (rowptr from cnt) =================

__global__ void k_scan1(const int* __restrict__ cnt, int n, int* __restrict__ excl,
                        int* __restrict__ blksum) {
    __shared__ int sh[TB];
    int t = threadIdx.x;
    int base = blockIdx.x * SCAN_CHUNK + t * SCAN_ELEMS;
    int v[SCAN_ELEMS];
    int tot = 0;
    #pragma unroll
    for (int i = 0; i < SCAN_ELEMS; i++) {
        int idx = base + i;
        int c = (idx < n) ? cnt[idx] : 0;
        v[i] = tot;
        tot += c;
    }
    sh[t] = tot;
    __syncthreads();
    for (int off = 1; off < TB; off <<= 1) {
        int x = (t >= off) ? sh[t - off] : 0;
        __syncthreads();
        sh[t] += x;
        __syncthreads();
    }
    int excl_t = sh[t] - tot;
    if (t == TB - 1) blksum[blockIdx.x] = sh[t];
    #pragma unroll
    for (int i = 0; i < SCAN_ELEMS; i++) {
        int idx = base + i;
        if (idx < n) excl[idx] = excl_t + v[i];
    }
}

__global__ void k_scan2(int* __restrict__ blksum, int nb) {
    __shared__ int sh[TB];
    int t = threadIdx.x;
    int val = (t < nb) ? blksum[t] : 0;
    sh[t] = val;
    __syncthreads();
    for (int off = 1; off < TB; off <<= 1) {
        int x = (t >= off) ? sh[t - off] : 0;
        __syncthreads();
        sh[t] += x;
        __syncthreads();
    }
    if (t < nb) blksum[t] = sh[t] - val;
}

__global__ void k_scan3(int* __restrict__ rowptr, const int* __restrict__ blkoff, int n, int E) {
    int i = blockIdx.x * blockDim.x + threadIdx.x;
    if (i < n) rowptr[i] += blkoff[i / SCAN_CHUNK];
    if (i == 0) rowptr[n] = E;
}

// ================= fast CSR build: bucketed 2-level partition =================

__global__ void k_p1a(const int* __restrict__ eidst, int E, int SH, int* __restrict__ offs) {
    __shared__ int h[256];
    int t = threadIdx.x;
    for (int j = t; j < 256; j += blockDim.x) h[j] = 0;
    __syncthreads();
    int base = blockIdx.x * P_CHUNK;
    for (int k = t; k < P_CHUNK; k += blockDim.x) {
        int e = base + k;
        if (e < E) atomicAdd(&h[eidst[e] >> SH], 1);
    }
    __syncthreads();
    for (int j = t; j < 256; j += blockDim.x) offs[blockIdx.x * 256 + j] = h[j];
}

__global__ void k_pscanA(int* __restrict__ offs, int nblk, int* __restrict__ btot) {
    __shared__ int sh[256];
    int t = threadIdx.x, b = blockIdx.x;
    int v = (t < nblk) ? offs[t * 256 + b] : 0;
    sh[t] = v;
    __syncthreads();
    for (int off = 1; off < 256; off <<= 1) {
        int x = (t >= off) ? sh[t - off] : 0;
        __syncthreads();
        sh[t] += x;
        __syncthreads();
    }
    if (t < nblk) offs[t * 256 + b] = sh[t] - v;
    if (t == 255) btot[b] = sh[255];
}

__global__ void k_pscan2(const int* __restrict__ btot, int* __restrict__ bbase, int E) {
    __shared__ int sh[256];
    int t = threadIdx.x;
    int v = btot[t];
    sh[t] = v;
    __syncthreads();
    for (int off = 1; off < 256; off <<= 1) {
        int x = (t >= off) ? sh[t - off] : 0;
        __syncthreads();
        sh[t] += x;
        __syncthreads();
    }
    bbase[t] = sh[t] - v;
    if (t == 255) bbase[256] = sh[255];
}

__global__ void k_p1b(const int* __restrict__ ei, int E, int SH,
                      const int* __restrict__ offs, const int* __restrict__ bbase,
                      unsigned* __restrict__ ebuf) {
    __shared__ int head[256];
    int t = threadIdx.x;
    for (int j = t; j < 256; j += blockDim.x) head[j] = bbase[j] + offs[blockIdx.x * 256 + j];
    __syncthreads();
    int base = blockIdx.x * P_CHUNK;
    unsigned mask = (1u << SH) - 1u;
    for (int k = t; k < P_CHUNK; k += blockDim.x) {
        int e = base + k;
        if (e < E) {
            int d = ei[E + e];
            unsigned s = (unsigned)ei[e];
            int p = atomicAdd(&head[d >> SH], 1);
            ebuf[p] = (s << SH) | ((unsigned)d & mask);
        }
    }
}

__global__ void k_p2a(const unsigned* __restrict__ ebuf, const int* __restrict__ bbase,
                      int SH, int n, int* __restrict__ cnt) {
    __shared__ int c[1024];
    int b = blockIdx.x, t = threadIdx.x;
    int d0 = b << SH;
    int w = 1 << SH;
    int nd = n - d0; if (nd > w) nd = w;
    for (int j = t; j < nd; j += blockDim.x) c[j] = 0;
    __syncthreads();
    int e0 = bbase[b], e1 = bbase[b + 1];
    unsigned mask = (unsigned)(w - 1);
    for (int e = e0 + t; e < e1; e += blockDim.x) atomicAdd(&c[ebuf[e] & mask], 1);
    __syncthreads();
    for (int j = t; j < nd; j += blockDim.x) cnt[d0 + j] = c[j];
}

__global__ void k_p2b(const unsigned* __restrict__ ebuf, const int* __restrict__ bbase,
                      const int* __restrict__ rowptr, int SH, int n, int* __restrict__ srcs) {
    __shared__ int head[1024];
    int b = blockIdx.x, t = threadIdx.x;
    int d0 = b << SH;
    int w = 1 << SH;
    int nd = n - d0; if (nd > w) nd = w;
    for (int j = t; j < nd; j += blockDim.x) head[j] = rowptr[d0 + j];
    __syncthreads();
    int e0 = bbase[b], e1 = bbase[b + 1];
    unsigned mask = (unsigned)(w - 1);
    for (int e = e0 + t; e < e1; e += blockDim.x) {
        unsigned pk = ebuf[e];
        int p = atomicAdd(&head[pk & mask], 1);
        srcs[p] = (int)(pk >> SH);
    }
}

// ================= legacy fallback CSR build =================

__global__ void k_hist(const int* __restrict__ ei, int E, int* __restrict__ cnt) {
    int e = blockIdx.x * blockDim.x + threadIdx.x;
    if (e < E) atomicAdd(&cnt[ei[E + e]], 1);
}
__global__ void k_headinit(const int* __restrict__ rowptr, int n, int* __restrict__ head) {
    int i = blockIdx.x * blockDim.x + threadIdx.x;
    if (i < n) head[i] = rowptr[i];
}
__global__ void k_scatter(const int* __restrict__ ei, int E, int* __restrict__ head,
                          int* __restrict__ srcs) {
    int e = blockIdx.x * blockDim.x + threadIdx.x;
    if (e < E) {
        int p = atomicAdd(&head[ei[E + e]], 1);
        srcs[p] = ei[e];
    }
}

// ================= weight precompute: g = Wh @ Wr[2:], c_h = bh . Wr[2:] =================

__global__ void k_wprep(const float* __restrict__ Wh, const float* __restrict__ bh,
                        const float* __restrict__ Wr, float* __restrict__ gbuf) {
    int t = threadIdx.x;
    if (t < 4) {
        float s = 0.f;
        for (int m = 0; m < LH; m++) s += Wh[t * LH + m] * Wr[2 + m];
        gbuf[t] = s;
    } else if (t == 4) {
        float s = 0.f;
        for (int m = 0; m < LH; m++) s += bh[m] * Wr[2 + m];
        gbuf[4] = s;
    }
}

// ================= cooperative mega-kernel: all node passes =================

__global__ __launch_bounds__(MTB, 4) void k_mega(
    const int* __restrict__ rowptr, const int* __restrict__ srcs,
    const float* __restrict__ x, const float* __restrict__ gbuf,
    const float* __restrict__ Wr, const float* __restrict__ br,
    const float* __restrict__ Wq, const float* __restrict__ bq,
    const float* __restrict__ Wpi, const float* __restrict__ bpi,
    int n,
    float4* __restrict__ xdt, float* __restrict__ s1t, float* __restrict__ rt,
    float* __restrict__ v0t, float* __restrict__ v1t, float4* __restrict__ tdt,
    float* __restrict__ out)
{
    cg::grid_group grid = cg::this_grid();

    __shared__ float wq[160];
    __shared__ float wbq[40];
    __shared__ float wpi[168];
    __shared__ float wm[16];   // 0-4: gbuf, 5-6: Wr, 7: br, 8-11: bpi
    __shared__ int eL[ECAP];
    __shared__ int she[2];

    int tid = threadIdx.x;
    int i0 = blockIdx.x * MTB;
    int i = i0 + tid;

    if (tid < 160) wq[tid] = Wq[tid];
    if (tid < 40) wbq[tid] = bq[tid];
    if (tid < 168) wpi[tid] = Wpi[tid];
    if (tid < 5) wm[tid] = gbuf[tid];
    if (tid == 5) wm[5] = Wr[0];
    if (tid == 6) wm[6] = Wr[1];
    if (tid == 7) wm[7] = br[0];
    if (tid >= 8 && tid < 12) wm[tid] = bpi[tid - 8];

    int b0 = 0, b1 = 0;
    if (i < n) { b0 = rowptr[i]; b1 = rowptr[i + 1]; }
    if (tid == 0) {
        she[0] = rowptr[i0 < n ? i0 : n];
        int iend = i0 + MTB; if (iend > n) iend = n;
        she[1] = rowptr[iend];
    }
    __syncthreads();
    int eb0 = she[0];
    int ecnt = she[1] - eb0;
    int ecap = ecnt < ECAP ? ecnt : ECAP;
    for (int j = tid; j < ecap; j += MTB) eL[j] = srcs[eb0 + j];

    // ---- phase A0: dinv + pre-scaled x ----
    float di = 0.f, xs0 = 0.f, xs1 = 0.f, xs2 = 0.f, xs3 = 0.f;
    int lb0 = 0, lb1 = 0, clo = 0, chi = 0;
    if (i < n) {
        di = 1.0f / sqrtf((float)(b1 - b0 + 1));
        float4 xv = ((const float4*)x)[i];
        xs0 = xv.x * di; xs1 = xv.y * di; xs2 = xv.z * di; xs3 = xv.w * di;
        xdt[i] = make_float4(xs0, xs1, xs2, xs3);
        lb0 = b0 - eb0; lb1 = b1 - eb0;
        clo = lb0 < ecap ? lb0 : ecap;
        chi = lb1 < ecap ? lb1 : ecap;
    }
    grid.sync();

    // ---- phase A1: A1 = P(x); s1 = A1.g + c_h ----
    float ax = 0.f, ay = 0.f, s1s = 0.f;
    if (i < n) {
        float a0x = xs0, a0y = xs1, a0z = xs2, a0w = xs3;
        float a1x = 0, a1y = 0, a1z = 0, a1w = 0;
        float a2x = 0, a2y = 0, a2z = 0, a2w = 0;
        float a3x = 0, a3y = 0, a3z = 0, a3w = 0;
        int j = clo;
        for (; j + 4 <= chi; j += 4) {
            float4 v0 = xdt[eL[j]], v1 = xdt[eL[j + 1]], v2 = xdt[eL[j + 2]], v3 = xdt[eL[j + 3]];
            a0x += v0.x; a0y += v0.y; a0z += v0.z; a0w += v0.w;
            a1x += v1.x; a1y += v1.y; a1z += v1.z; a1w += v1.w;
            a2x += v2.x; a2y += v2.y; a2z += v2.z; a2w += v2.w;
            a3x += v3.x; a3y += v3.y; a3z += v3.z; a3w += v3.w;
        }
        for (; j < chi; ++j) {
            float4 v0 = xdt[eL[j]];
            a0x += v0.x; a0y += v0.y; a0z += v0.z; a0w += v0.w;
        }
        if (lb1 > ecap) {
            int eg = eb0 + (lb0 > ecap ? lb0 : ecap);
            for (int e = eg; e < eb0 + lb1; ++e) {
                float4 v0 = xdt[srcs[e]];
                a0x += v0.x; a0y += v0.y; a0z += v0.z; a0w += v0.w;
            }
        }
        ax = ((a0x + a1x) + (a2x + a3x)) * di;
        ay = ((a0y + a1y) + (a2y + a3y)) * di;
        float az = ((a0z + a1z) + (a2z + a3z)) * di;
        float aw = ((a0w + a1w) + (a2w + a3w)) * di;
        float s1 = ax * wm[0] + ay * wm[1] + az * wm[2] + aw * wm[3] + wm[4];
        s1s = s1 * di;
        s1t[i] = s1s;
    }
    grid.sync();

    // ---- phase R: r = A1.xy@Wr + P(s1) + br ----
    float rs = 0.f;
    if (i < n) {
        float c0 = s1s, c1 = 0, c2 = 0, c3 = 0;
        int j = clo;
        for (; j + 4 <= chi; j += 4) {
            c0 += s1t[eL[j]]; c1 += s1t[eL[j + 1]]; c2 += s1t[eL[j + 2]]; c3 += s1t[eL[j + 3]];
        }
        for (; j < chi; ++j) c0 += s1t[eL[j]];
        if (lb1 > ecap) {
            int eg = eb0 + (lb0 > ecap ? lb0 : ecap);
            for (int e = eg; e < eb0 + lb1; ++e) c0 += s1t[srcs[e]];
        }
        float Ps1 = ((c0 + c1) + (c2 + c3)) * di;
        float r = ax * wm[5] + ay * wm[6] + Ps1 + wm[7];
        rs = r * di;
        rt[i] = rs;
    }
    grid.sync();

    // ---- phase Pr: pr = P(r); base_j; first v ----
    float base[LQ];
    float vs = 0.f;
    if (i < n) {
        float c0 = rs, c1 = 0, c2 = 0, c3 = 0;
        int j = clo;
        for (; j + 4 <= chi; j += 4) {
            c0 += rt[eL[j]]; c1 += rt[eL[j + 1]]; c2 += rt[eL[j + 2]]; c3 += rt[eL[j + 3]];
        }
        for (; j < chi; ++j) c0 += rt[eL[j]];
        if (lb1 > ecap) {
            int eg = eb0 + (lb0 > ecap ? lb0 : ecap);
            for (int e = eg; e < eb0 + lb1; ++e) c0 += rt[srcs[e]];
        }
        float pr = ((c0 + c1) + (c2 + c3)) * di;
        float m = -1e30f;
        #pragma unroll
        for (int jj = 0; jj < LQ; jj++) {
            base[jj] = fmaf(ax, wq[jj], fmaf(ay, wq[LQ + jj], fmaf(pr, wq[2 * LQ + jj], wbq[jj])));
            m = fmaxf(m, base[jj]);
        }
        vs = m * di;
        v0t[i] = vs;
    }
    grid.sync();

    // ---- 18 value iterations ----
    float* vin = v0t;
    float* vout = v1t;
    for (int it = 0; it < 18; ++it) {
        float nvs = 0.f;
        if (i < n) {
            float c0 = vs, c1 = 0, c2 = 0, c3 = 0;
            int j = clo;
            for (; j + 4 <= chi; j += 4) {
                c0 += vin[eL[j]]; c1 += vin[eL[j + 1]]; c2 += vin[eL[j + 2]]; c3 += vin[eL[j + 3]];
            }
            for (; j < chi; ++j) c0 += vin[eL[j]];
            if (lb1 > ecap) {
                int eg = eb0 + (lb0 > ecap ? lb0 : ecap);
                for (int e = eg; e < eb0 + lb1; ++e) c0 += vin[srcs[e]];
            }
            float pv = ((c0 + c1) + (c2 + c3)) * di;
            float m = -1e30f;
            #pragma unroll
            for (int jj = 0; jj < LQ; jj++) m = fmaxf(m, fmaf(pv, wq[3 * LQ + jj], base[jj]));
            nvs = m * di;
            vout[i] = nvs;
        }
        vs = nvs;
        float* tmp = vin; vin = vout; vout = tmp;
        grid.sync();
    }

    // ---- final: 20th q -> t = q @ Wpi[2:] ----
    float t0s = 0.f, t1s = 0.f, t2s = 0.f, t3s = 0.f;
    if (i < n) {
        float c0 = vs, c1 = 0, c2 = 0, c3 = 0;
        int j = clo;
        for (; j + 4 <= chi; j += 4) {
            c0 += vin[eL[j]]; c1 += vin[eL[j + 1]]; c2 += vin[eL[j + 2]]; c3 += vin[eL[j + 3]];
        }
        for (; j < chi; ++j) c0 += vin[eL[j]];
        if (lb1 > ecap) {
            int eg = eb0 + (lb0 > ecap ? lb0 : ecap);
            for (int e = eg; e < eb0 + lb1; ++e) c0 += vin[srcs[e]];
        }
        float pv = ((c0 + c1) + (c2 + c3)) * di;
        float t0 = 0, t1 = 0, t2 = 0, t3 = 0;
        #pragma unroll
        for (int jj = 0; jj < LQ; jj++) {
            float q = fmaf(pv, wq[3 * LQ + jj], base[jj]);
            t0 = fmaf(q, wpi[(2 + jj) * 4 + 0], t0);
            t1 = fmaf(q, wpi[(2 + jj) * 4 + 1], t1);
            t2 = fmaf(q, wpi[(2 + jj) * 4 + 2], t2);
            t3 = fmaf(q, wpi[(2 + jj) * 4 + 3], t3);
        }
        t0s = t0 * di; t1s = t1 * di; t2s = t2 * di; t3s = t3 * di;
        tdt[i] = make_float4(t0s, t1s, t2s, t3s);
    }
    grid.sync();

    // ---- logits + softmax ----
    if (i < n) {
        float a0x = t0s, a0y = t1s, a0z = t2s, a0w = t3s;
        float a1x = 0, a1y = 0, a1z = 0, a1w = 0;
        float a2x = 0, a2y = 0, a2z = 0, a2w = 0;
        float a3x = 0, a3y = 0, a3z = 0, a3w = 0;
        int j = clo;
        for (; j + 4 <= chi; j += 4) {
            float4 v0 = tdt[eL[j]], v1 = tdt[eL[j + 1]], v2 = tdt[eL[j + 2]], v3 = tdt[eL[j + 3]];
            a0x += v0.x; a0y += v0.y; a0z += v0.z; a0w += v0.w;
            a1x += v1.x; a1y += v1.y; a1z += v1.z; a1w += v1.w;
            a2x += v2.x; a2y += v2.y; a2z += v2.z; a2w += v2.w;
            a3x += v3.x; a3y += v3.y; a3z += v3.z; a3w += v3.w;
        }
        for (; j < chi; ++j) {
            float4 v0 = tdt[eL[j]];
            a0x += v0.x; a0y += v0.y; a0z += v0.z; a0w += v0.w;
        }
        if (lb1 > ecap) {
            int eg = eb0 + (lb0 > ecap ? lb0 : ecap);
            for (int e = eg; e < eb0 + lb1; ++e) {
                float4 v0 = tdt[srcs[e]];
                a0x += v0.x; a0y += v0.y; a0z += v0.z; a0w += v0.w;
            }
        }
        float l0 = ax * wpi[0] + ay * wpi[4] + ((a0x + a1x) + (a2x + a3x)) * di + wm[8];
        float l1 = ax * wpi[1] + ay * wpi[5] + ((a0y + a1y) + (a2y + a3y)) * di + wm[9];
        float l2 = ax * wpi[2] + ay * wpi[6] + ((a0z + a1z) + (a2z + a3z)) * di + wm[10];
        float l3 = ax * wpi[3] + ay * wpi[7] + ((a0w + a1w) + (a2w + a3w)) * di + wm[11];
        float mx = fmaxf(fmaxf(l0, l1), fmaxf(l2, l3));
        float e0 = expf(l0 - mx), e1 = expf(l1 - mx), e2 = expf(l2 - mx), e3 = expf(l3 - mx);
        float inv = 1.0f / (e0 + e1 + e2 + e3);
        ((float4*)out)[i] = make_float4(l0, l1, l2, l3);
        ((float4*)(out + (size_t)n * 4))[i] = make_float4(e0 * inv, e1 * inv, e2 * inv, e3 * inv);
    }
}

// ================= legacy node-pass kernels (fallback) =================

__global__ void k_dinvprep(const int* __restrict__ rowptr, const float* __restrict__ x,
                           int n, float* __restrict__ dinv, float4* __restrict__ xd) {
    int i = blockIdx.x * blockDim.x + threadIdx.x;
    if (i >= n) return;
    int deg = rowptr[i + 1] - rowptr[i];
    float di = 1.0f / sqrtf((float)(deg + 1));
    dinv[i] = di;
    float4 xv = ((const float4*)x)[i];
    xd[i] = make_float4(xv.x * di, xv.y * di, xv.z * di, xv.w * di);
}

__global__ void k_aggA1(const int* __restrict__ rowptr, const int* __restrict__ srcs,
                        const float4* __restrict__ xd, const float* __restrict__ dinv,
                        const float* __restrict__ gbuf, int n,
                        float2* __restrict__ axy, float* __restrict__ s1d) {
    int i = blockIdx.x * blockDim.x + threadIdx.x;
    if (i >= n) return;
    int b0 = rowptr[i], b1 = rowptr[i + 1];
    float4 a0 = xd[i];
    float4 a1 = make_float4(0, 0, 0, 0), a2 = a1, a3 = a1;
    int e = b0;
    for (; e + 4 <= b1; e += 4) {
        float4 v0 = xd[srcs[e]], v1 = xd[srcs[e + 1]], v2 = xd[srcs[e + 2]], v3 = xd[srcs[e + 3]];
        a0.x += v0.x; a0.y += v0.y; a0.z += v0.z; a0.w += v0.w;
        a1.x += v1.x; a1.y += v1.y; a1.z += v1.z; a1.w += v1.w;
        a2.x += v2.x; a2.y += v2.y; a2.z += v2.z; a2.w += v2.w;
        a3.x += v3.x; a3.y += v3.y; a3.z += v3.z; a3.w += v3.w;
    }
    for (; e < b1; ++e) {
        float4 v = xd[srcs[e]];
        a0.x += v.x; a0.y += v.y; a0.z += v.z; a0.w += v.w;
    }
    float di = dinv[i];
    float ax = ((a0.x + a1.x) + (a2.x + a3.x)) * di;
    float ay = ((a0.y + a1.y) + (a2.y + a3.y)) * di;
    float az = ((a0.z + a1.z) + (a2.z + a3.z)) * di;
    float aw = ((a0.w + a1.w) + (a2.w + a3.w)) * di;
    axy[i] = make_float2(ax, ay);
    float s1v = ax * gbuf[0] + ay * gbuf[1] + az * gbuf[2] + aw * gbuf[3] + gbuf[4];
    s1d[i] = s1v * di;
}

__global__ void k_aggR(const int* __restrict__ rowptr, const int* __restrict__ srcs,
                       const float* __restrict__ s1d, const float* __restrict__ dinv,
                       const float2* __restrict__ axy, const float* __restrict__ Wr,
                       const float* __restrict__ br, int n, float* __restrict__ rd) {
    int i = blockIdx.x * blockDim.x + threadIdx.x;
    if (i >= n) return;
    int b0 = rowptr[i], b1 = rowptr[i + 1];
    float c0 = s1d[i], c1 = 0.f, c2 = 0.f, c3 = 0.f;
    int e = b0;
    for (; e + 4 <= b1; e += 4) {
        c0 += s1d[srcs[e]]; c1 += s1d[srcs[e + 1]]; c2 += s1d[srcs[e + 2]]; c3 += s1d[srcs[e + 3]];
    }
    for (; e < b1; ++e) c0 += s1d[srcs[e]];
    float di = dinv[i];
    float Ps1 = ((c0 + c1) + (c2 + c3)) * di;
    float2 a = axy[i];
    float r = a.x * Wr[0] + a.y * Wr[1] + Ps1 + br[0];
    rd[i] = r * di;
}

__global__ void k_aggPr(const int* __restrict__ rowptr, const int* __restrict__ srcs,
                        const float* __restrict__ rd, const float* __restrict__ dinv,
                        const float2* __restrict__ axy, const float* __restrict__ Wq,
                        const float* __restrict__ bq, int n,
                        float4* __restrict__ nd, float* __restrict__ vd0) {
    int i = blockIdx.x * blockDim.x + threadIdx.x;
    if (i >= n) return;
    int b0 = rowptr[i], b1 = rowptr[i + 1];
    float c0 = rd[i], c1 = 0.f, c2 = 0.f, c3 = 0.f;
    int e = b0;
    for (; e + 4 <= b1; e += 4) {
        c0 += rd[srcs[e]]; c1 += rd[srcs[e + 1]]; c2 += rd[srcs[e + 2]]; c3 += rd[srcs[e + 3]];
    }
    for (; e < b1; ++e) c0 += rd[srcs[e]];
    float di = dinv[i];
    float pr = ((c0 + c1) + (c2 + c3)) * di;
    float2 a = axy[i];
    nd[i] = make_float4(a.x, a.y, pr, di);
    float m = -1e30f;
    #pragma unroll
    for (int j = 0; j < LQ; j++) {
        float q = fmaf(a.x, Wq[j], fmaf(a.y, Wq[LQ + j], fmaf(pr, Wq[2 * LQ + j], bq[j])));
        m = fmaxf(m, q);
    }
    vd0[i] = m * di;
}

__global__ void k_iter(const int* __restrict__ rowptr, const int* __restrict__ srcs,
                       const float* __restrict__ vdin, const float4* __restrict__ nd,
                       const float* __restrict__ Wq, const float* __restrict__ bq, int n,
                       float* __restrict__ vdout) {
    int i = blockIdx.x * blockDim.x + threadIdx.x;
    if (i >= n) return;
    int b0 = rowptr[i], b1 = rowptr[i + 1];
    float c0 = vdin[i], c1 = 0.f, c2 = 0.f, c3 = 0.f;
    int e = b0;
    for (; e + 4 <= b1; e += 4) {
        c0 += vdin[srcs[e]]; c1 += vdin[srcs[e + 1]]; c2 += vdin[srcs[e + 2]]; c3 += vdin[srcs[e + 3]];
    }
    for (; e < b1; ++e) c0 += vdin[srcs[e]];
    float4 c = nd[i];
    float pv = ((c0 + c1) + (c2 + c3)) * c.w;
    float m = -1e30f;
    #pragma unroll
    for (int j = 0; j < LQ; j++) {
        float q = fmaf(c.x, Wq[j], fmaf(c.y, Wq[LQ + j],
                  fmaf(c.z, Wq[2 * LQ + j], fmaf(pv, Wq[3 * LQ + j], bq[j]))));
        m = fmaxf(m, q);
    }
    vdout[i] = m * c.w;
}

__global__ void k_final(const int* __restrict__ rowptr, const int* __restrict__ srcs,
                        const float* __restrict__ vdin, const float4* __restrict__ nd,
                        const float* __restrict__ Wq, const float* __restrict__ bq,
                        const float* __restrict__ Wpi, int n, float4* __restrict__ td) {
    int i = blockIdx.x * blockDim.x + threadIdx.x;
    if (i >= n) return;
    int b0 = rowptr[i], b1 = rowptr[i + 1];
    float c0 = vdin[i], c1 = 0.f, c2 = 0.f, c3 = 0.f;
    int e = b0;
    for (; e + 4 <= b1; e += 4) {
        c0 += vdin[srcs[e]]; c1 += vdin[srcs[e + 1]]; c2 += vdin[srcs[e + 2]]; c3 += vdin[srcs[e + 3]];
    }
    for (; e < b1; ++e) c0 += vdin[srcs[e]];
    float4 c = nd[i];
    float pv = ((c0 + c1) + (c2 + c3)) * c.w;
    float t0 = 0.f, t1 = 0.f, t2 = 0.f, t3 = 0.f;
    #pragma unroll
    for (int j = 0; j < LQ; j++) {
        float q = fmaf(c.x, Wq[j], fmaf(c.y, Wq[LQ + j],
                  fmaf(c.z, Wq[2 * LQ + j], fmaf(pv, Wq[3 * LQ + j], bq[j]))));
        const float* wp = &Wpi[(2 + j) * 4];
        t0 = fmaf(q, wp[0], t0); t1 = fmaf(q, wp[1], t1);
        t2 = fmaf(q, wp[2], t2); t3 = fmaf(q, wp[3], t3);
    }
    td[i] = make_float4(t0 * c.w, t1 * c.w, t2 * c.w, t3 * c.w);
}

__global__ void k_logits(const int* __restrict__ rowptr, const int* __restrict__ srcs,
                         const float4* __restrict__ td, const float4* __restrict__ nd,
                         const float* __restrict__ Wpi, const float* __restrict__ bpi,
                         int n, float* __restrict__ out) {
    int i = blockIdx.x * blockDim.x + threadIdx.x;
    if (i >= n) return;
    int b0 = rowptr[i], b1 = rowptr[i + 1];
    float4 a0 = td[i];
    float4 a1 = make_float4(0, 0, 0, 0), a2 = a1, a3 = a1;
    int e = b0;
    for (; e + 4 <= b1; e += 4) {
        float4 v0 = td[srcs[e]], v1 = td[srcs[e + 1]], v2 = td[srcs[e + 2]], v3 = td[srcs[e + 3]];
        a0.x += v0.x; a0.y += v0.y; a0.z += v0.z; a0.w += v0.w;
        a1.x += v1.x; a1.y += v1.y; a1.z += v1.z; a1.w += v1.w;
        a2.x += v2.x; a2.y += v2.y; a2.z += v2.z; a2.w += v2.w;
        a3.x += v3.x; a3.y += v3.y; a3.z += v3.z; a3.w += v3.w;
    }
    for (; e < b1; ++e) {
        float4 v = td[srcs[e]];
        a0.x += v.x; a0.y += v.y; a0.z += v.z; a0.w += v.w;
    }
    float4 c = nd[i];
    float di = c.w;
    float l0 = c.x * Wpi[0] + c.y * Wpi[4] + ((a0.x + a1.x) + (a2.x + a3.x)) * di + bpi[0];
    float l1 = c.x * Wpi[1] + c.y * Wpi[5] + ((a0.y + a1.y) + (a2.y + a3.y)) * di + bpi[1];
    float l2 = c.x * Wpi[2] + c.y * Wpi[6] + ((a0.z + a1.z) + (a2.z + a3.z)) * di + bpi[2];
    float l3 = c.x * Wpi[3] + c.y * Wpi[7] + ((a0.w + a1.w) + (a2.w + a3.w)) * di + bpi[3];
    float mx = fmaxf(fmaxf(l0, l1), fmaxf(l2, l3));
    float e0 = expf(l0 - mx), e1 = expf(l1 - mx), e2 = expf(l2 - mx), e3 = expf(l3 - mx);
    float inv = 1.0f / (e0 + e1 + e2 + e3);
    size_t base = (size_t)i * 4;
    out[base + 0] = l0; out[base + 1] = l1; out[base + 2] = l2; out[base + 3] = l3;
    size_t pbase = (size_t)n * 4 + base;
    out[pbase + 0] = e0 * inv; out[pbase + 1] = e1 * inv;
    out[pbase + 2] = e2 * inv; out[pbase + 3] = e3 * inv;
}

extern "C" void kernel_launch(void* const* d_in, const int* in_sizes, int n_in,
                              void* d_out, int out_size, void* d_ws, size_t ws_size,
                              hipStream_t stream) {
    const float* x = (const float*)d_in[0];
    const int* ei = (const int*)d_in[1];   // int32: harness converts integer inputs
    const float* Wh = (const float*)d_in[2];
    const float* bh = (const float*)d_in[3];
    const float* Wr = (const float*)d_in[4];
    const float* br = (const float*)d_in[5];
    const float* Wq = (const float*)d_in[6];
    const float* bq = (const float*)d_in[7];
    const float* Wpi = (const float*)d_in[8];
    const float* bpi = (const float*)d_in[9];
    int n = in_sizes[0] / 4;
    int E = in_sizes[1] / 2;
    float* out = (float*)d_out;

    int SH = 0;
    while ((((n - 1) >> SH) + 1) > 256) SH++;
    int NB = ((n - 1) >> SH) + 1;
    int nblk2 = (E + P_CHUNK - 1) / P_CHUNK;
    bool fast = (SH <= 10) && (nblk2 <= 256) &&
                ((unsigned long long)n <= (1ull << (32 - SH)));

    char* w = (char*)d_ws;
    size_t off = 0;
    auto alloc = [&](size_t bytes) -> void* {
        void* p = w + off;
        off += (bytes + 255) & ~(size_t)255;
        return p;
    };

    int nblk1 = (n + SCAN_CHUNK - 1) / SCAN_CHUNK;
    int* rowptr = (int*)alloc((size_t)(n + 1) * 4);
    int* srcs = (int*)alloc((size_t)E * 4);
    unsigned* ebuf = (unsigned*)alloc((size_t)E * 4);
    int* cnt = (int*)alloc((size_t)n * 4);
    int* blksum = (int*)alloc((size_t)nblk1 * 4);
    int* btot = (int*)alloc(256 * 4);
    int* bbase = (int*)alloc(257 * 4);
    float* gbuf = (float*)alloc(8 * 4);
    int* offs = (int*)alloc((size_t)(fast ? nblk2 : 1) * 256 * 4);
    float4* xd = (float4*)alloc((size_t)n * 16);
    float4* td = (float4*)alloc((size_t)n * 16);
    float* s1t = (float*)alloc((size_t)n * 4);
    float* rt = (float*)alloc((size_t)n * 4);
    float* v0t = (float*)alloc((size_t)n * 4);
    float* v1t = (float*)alloc((size_t)n * 4);
    float* dinv = (float*)alloc((size_t)n * 4);      // legacy path
    float2* axy = (float2*)alloc((size_t)n * 8);     // legacy path
    float4* nd = (float4*)alloc((size_t)n * 16);     // legacy path
    int* head = (int*)alloc((size_t)n * 4);          // legacy path

    int gN = (n + TB - 1) / TB;
    int gE = (E + TB - 1) / TB;

    if (fast) {
        k_p1a<<<nblk2, PB, 0, stream>>>(ei + E, E, SH, offs);
        k_pscanA<<<256, 256, 0, stream>>>(offs, nblk2, btot);
        k_pscan2<<<1, 256, 0, stream>>>(btot, bbase, E);
        k_p1b<<<nblk2, PB, 0, stream>>>(ei, E, SH, offs, bbase, ebuf);
        k_p2a<<<NB, PB, 0, stream>>>(ebuf, bbase, SH, n, cnt);
        k_scan1<<<nblk1, TB, 0, stream>>>(cnt, n, rowptr, blksum);
        k_scan2<<<1, TB, 0, stream>>>(blksum, nblk1);
        k_scan3<<<gN, TB, 0, stream>>>(rowptr, blksum, n, E);
        k_p2b<<<NB, PB, 0, stream>>>(ebuf, bbase, rowptr, SH, n, srcs);
    } else {
        hipMemsetAsync(cnt, 0, (size_t)n * 4, stream);
        k_hist<<<gE, TB, 0, stream>>>(ei, E, cnt);
        k_scan1<<<nblk1, TB, 0, stream>>>(cnt, n, rowptr, blksum);
        k_scan2<<<1, TB, 0, stream>>>(blksum, nblk1);
        k_scan3<<<gN, TB, 0, stream>>>(rowptr, blksum, n, E);
        k_headinit<<<gN, TB, 0, stream>>>(rowptr, n, head);
        k_scatter<<<gE, TB, 0, stream>>>(ei, E, head, srcs);
    }

    k_wprep<<<1, TB, 0, stream>>>(Wh, bh, Wr, gbuf);

    // ---- cooperative mega-kernel if it can be co-resident; else legacy ----
    int NBLK = (n + MTB - 1) / MTB;
    bool coop_ok = false;
    {
        int occ = 0;
        hipError_t oerr = hipOccupancyMaxActiveBlocksPerMultiprocessor(
            &occ, (const void*)k_mega, MTB, 0);
        int dev = 0;
        hipGetDevice(&dev);
        int numCU = 0;
        hipDeviceGetAttribute(&numCU, hipDeviceAttributeMultiprocessorCount, dev);
        if (oerr == hipSuccess && occ > 0 && numCU > 0 &&
            (long long)occ * numCU >= (long long)NBLK) {
            coop_ok = true;
        }
    }
    if (coop_ok) {
        void* args[] = {&rowptr, &srcs, (void*)&x, &gbuf, (void*)&Wr, (void*)&br,
                        (void*)&Wq, (void*)&bq, (void*)&Wpi, (void*)&bpi, &n,
                        &xd, &s1t, &rt, &v0t, &v1t, &td, &out};
        hipError_t lerr = hipLaunchCooperativeKernel((void*)k_mega, dim3(NBLK), dim3(MTB),
                                                     args, 0, stream);
        if (lerr != hipSuccess) coop_ok = false;
    }
    if (!coop_ok) {
        k_dinvprep<<<gN, TB, 0, stream>>>(rowptr, x, n, dinv, xd);
        k_aggA1<<<gN, TB, 0, stream>>>(rowptr, srcs, xd, dinv, gbuf, n, axy, s1t);
        k_aggR<<<gN, TB, 0, stream>>>(rowptr, srcs, s1t, dinv, axy, Wr, br, n, rt);
        k_aggPr<<<gN, TB, 0, stream>>>(rowptr, srcs, rt, dinv, axy, Wq, bq, n, nd, v0t);
        float* vin = v0t;
        float* vout = v1t;
        for (int it = 2; it <= 19; ++it) {
            k_iter<<<gN, TB, 0, stream>>>(rowptr, srcs, vin, nd, Wq, bq, n, vout);
            float* tmp = vin; vin = vout; vout = tmp;
        }
        k_final<<<gN, TB, 0, stream>>>(rowptr, srcs, vin, nd, Wq, bq, Wpi, n, td);
        k_logits<<<gN, TB, 0, stream>>>(rowptr, srcs, td, nd, Wpi, bpi, n, out);
    }
}

// Round 6
// 330.134 us; speedup vs baseline: 1.8536x; 1.0390x over previous
//
#include <hip/hip_runtime.h>
#include <math.h>

#define TB 256
#define PB 512
#define SCAN_ELEMS 8
#define SCAN_CHUNK (TB * SCAN_ELEMS)
#define P_CHUNK 8192
#define LQ 40
#define LH 150
#define ECAP2 4096

// ================= fast CSR build: bucketed 2-level partition =================
// bucket = dst >> SH, <=256 buckets; edge packed as (src<<SH)|(dst&mask)

__global__ void k_p1a(const int* __restrict__ eidst, int E, int SH, int* __restrict__ offs,
                      const float* __restrict__ Wh, const float* __restrict__ bh,
                      const float* __restrict__ Wr, float* __restrict__ gbuf) {
    __shared__ int h[256];
    int t = threadIdx.x;
    for (int j = t; j < 256; j += blockDim.x) h[j] = 0;
    __syncthreads();
    int base = blockIdx.x * P_CHUNK;
    for (int k = t; k < P_CHUNK; k += blockDim.x) {
        int e = base + k;
        if (e < E) atomicAdd(&h[eidst[e] >> SH], 1);
    }
    // fused wprep: g = Wh @ Wr[2:], c_h = bh . Wr[2:]
    if (blockIdx.x == 0 && t < 5) {
        float s = 0.f;
        if (t < 4) { for (int m = 0; m < LH; m++) s += Wh[t * LH + m] * Wr[2 + m]; }
        else       { for (int m = 0; m < LH; m++) s += bh[m] * Wr[2 + m]; }
        gbuf[t] = s;
    }
    __syncthreads();
    for (int j = t; j < 256; j += blockDim.x) offs[blockIdx.x * 256 + j] = h[j];
}

__global__ void k_pscanA(int* __restrict__ offs, int nblk, int* __restrict__ btot) {
    __shared__ int sh[256];
    int t = threadIdx.x, b = blockIdx.x;
    int v = (t < nblk) ? offs[t * 256 + b] : 0;
    sh[t] = v;
    __syncthreads();
    for (int off = 1; off < 256; off <<= 1) {
        int x = (t >= off) ? sh[t - off] : 0;
        __syncthreads();
        sh[t] += x;
        __syncthreads();
    }
    if (t < nblk) offs[t * 256 + b] = sh[t] - v;
    if (t == 255) btot[b] = sh[255];
}

__global__ void k_pscan2(const int* __restrict__ btot, int* __restrict__ bbase, int E) {
    __shared__ int sh[256];
    int t = threadIdx.x;
    int v = btot[t];
    sh[t] = v;
    __syncthreads();
    for (int off = 1; off < 256; off <<= 1) {
        int x = (t >= off) ? sh[t - off] : 0;
        __syncthreads();
        sh[t] += x;
        __syncthreads();
    }
    bbase[t] = sh[t] - v;
    if (t == 255) bbase[256] = sh[255];
}

__global__ void k_p1b(const int* __restrict__ ei, int E, int SH,
                      const int* __restrict__ offs, const int* __restrict__ bbase,
                      unsigned* __restrict__ ebuf) {
    __shared__ int head[256];
    int t = threadIdx.x;
    for (int j = t; j < 256; j += blockDim.x) head[j] = bbase[j] + offs[blockIdx.x * 256 + j];
    __syncthreads();
    int base = blockIdx.x * P_CHUNK;
    unsigned mask = (1u << SH) - 1u;
    for (int k = t; k < P_CHUNK; k += blockDim.x) {
        int e = base + k;
        if (e < E) {
            int d = ei[E + e];
            unsigned s = (unsigned)ei[e];
            int p = atomicAdd(&head[d >> SH], 1);
            ebuf[p] = (s << SH) | ((unsigned)d & mask);
        }
    }
}

// per-dst counts via LDS atomics, then per-bucket LDS scan -> GLOBAL rowptr
// (rowptr[d] = bbase[bucket] + prefix-within-bucket; replaces 3 scan kernels)
__global__ void k_p2a(const unsigned* __restrict__ ebuf, const int* __restrict__ bbase,
                      int SH, int n, int E, int NBb, int* __restrict__ rowptr) {
    __shared__ int c[1024];
    __shared__ int ps[PB];
    int b = blockIdx.x, t = threadIdx.x;
    int d0 = b << SH;
    int w = 1 << SH;
    int ndd = n - d0; if (ndd > w) ndd = w;
    for (int j = t; j < 1024; j += blockDim.x) c[j] = 0;
    __syncthreads();
    int e0 = bbase[b], e1 = bbase[b + 1];
    unsigned mask = (unsigned)(w - 1);
    for (int e = e0 + t; e < e1; e += blockDim.x) atomicAdd(&c[ebuf[e] & mask], 1);
    __syncthreads();
    int s0 = c[2 * t], s1v = c[2 * t + 1];
    ps[t] = s0 + s1v;
    __syncthreads();
    for (int off = 1; off < PB; off <<= 1) {
        int x = (t >= off) ? ps[t - off] : 0;
        __syncthreads();
        ps[t] += x;
        __syncthreads();
    }
    int ex = ps[t] - (s0 + s1v);  // exclusive pair-prefix
    int bb = bbase[b];
    if (2 * t < ndd)     rowptr[d0 + 2 * t]     = bb + ex;
    if (2 * t + 1 < ndd) rowptr[d0 + 2 * t + 1] = bb + ex + s0;
    if (b == NBb - 1 && t == 0) rowptr[n] = E;
}

// final scatter: writes confined to this bucket's ~32KB srcs range (L2-resident)
__global__ void k_p2b(const unsigned* __restrict__ ebuf, const int* __restrict__ bbase,
                      const int* __restrict__ rowptr, int SH, int n, int* __restrict__ srcs) {
    __shared__ int head[1024];
    int b = blockIdx.x, t = threadIdx.x;
    int d0 = b << SH;
    int w = 1 << SH;
    int ndd = n - d0; if (ndd > w) ndd = w;
    for (int j = t; j < ndd; j += blockDim.x) head[j] = rowptr[d0 + j];
    __syncthreads();
    int e0 = bbase[b], e1 = bbase[b + 1];
    unsigned mask = (unsigned)(w - 1);
    for (int e = e0 + t; e < e1; e += blockDim.x) {
        unsigned pk = ebuf[e];
        int p = atomicAdd(&head[pk & mask], 1);
        srcs[p] = (int)(pk >> SH);
    }
}

// ================= legacy fallback CSR build (odd shapes only) =================

__global__ void k_hist(const int* __restrict__ ei, int E, int* __restrict__ cnt) {
    int e = blockIdx.x * blockDim.x + threadIdx.x;
    if (e < E) atomicAdd(&cnt[ei[E + e]], 1);
}
__global__ void k_scan1(const int* __restrict__ cnt, int n, int* __restrict__ excl,
                        int* __restrict__ blksum) {
    __shared__ int sh[TB];
    int t = threadIdx.x;
    int base = blockIdx.x * SCAN_CHUNK + t * SCAN_ELEMS;
    int v[SCAN_ELEMS];
    int tot = 0;
    #pragma unroll
    for (int i = 0; i < SCAN_ELEMS; i++) {
        int idx = base + i;
        int c = (idx < n) ? cnt[idx] : 0;
        v[i] = tot;
        tot += c;
    }
    sh[t] = tot;
    __syncthreads();
    for (int off = 1; off < TB; off <<= 1) {
        int x = (t >= off) ? sh[t - off] : 0;
        __syncthreads();
        sh[t] += x;
        __syncthreads();
    }
    int excl_t = sh[t] - tot;
    if (t == TB - 1) blksum[blockIdx.x] = sh[t];
    #pragma unroll
    for (int i = 0; i < SCAN_ELEMS; i++) {
        int idx = base + i;
        if (idx < n) excl[idx] = excl_t + v[i];
    }
}
__global__ void k_scan2(int* __restrict__ blksum, int nb) {
    __shared__ int sh[TB];
    int t = threadIdx.x;
    int val = (t < nb) ? blksum[t] : 0;
    sh[t] = val;
    __syncthreads();
    for (int off = 1; off < TB; off <<= 1) {
        int x = (t >= off) ? sh[t - off] : 0;
        __syncthreads();
        sh[t] += x;
        __syncthreads();
    }
    if (t < nb) blksum[t] = sh[t] - val;
}
__global__ void k_scan3(int* __restrict__ rowptr, const int* __restrict__ blkoff, int n, int E) {
    int i = blockIdx.x * blockDim.x + threadIdx.x;
    if (i < n) rowptr[i] += blkoff[i / SCAN_CHUNK];
    if (i == 0) rowptr[n] = E;
}
__global__ void k_headinit(const int* __restrict__ rowptr, int n, int* __restrict__ head) {
    int i = blockIdx.x * blockDim.x + threadIdx.x;
    if (i < n) head[i] = rowptr[i];
}
__global__ void k_scatter(const int* __restrict__ ei, int E, int* __restrict__ head,
                          int* __restrict__ srcs) {
    int e = blockIdx.x * blockDim.x + threadIdx.x;
    if (e < E) {
        int p = atomicAdd(&head[ei[E + e]], 1);
        srcs[p] = ei[e];
    }
}
__global__ void k_wprep(const float* __restrict__ Wh, const float* __restrict__ bh,
                        const float* __restrict__ Wr, float* __restrict__ gbuf) {
    int t = threadIdx.x;
    if (t < 4) {
        float s = 0.f;
        for (int m = 0; m < LH; m++) s += Wh[t * LH + m] * Wr[2 + m];
        gbuf[t] = s;
    } else if (t == 4) {
        float s = 0.f;
        for (int m = 0; m < LH; m++) s += bh[m] * Wr[2 + m];
        gbuf[4] = s;
    }
}

// ================= node passes: LDS edge-slab versions =================
// Per block: contiguous CSR slab -> coalesced load into LDS; per-thread
// gathers read indices from LDS (LGKM pipe) instead of 8 strided VMEM streams.

#define SLAB_HEAD()                                                         \
    int tid = threadIdx.x;                                                  \
    int i0 = blockIdx.x * TB;                                               \
    int i = i0 + tid;                                                       \
    if (tid == 0) {                                                         \
        int bhi = i0 + TB; if (bhi > n) bhi = n;                            \
        sb2[0] = rowptr[i0];                                                \
        sb2[1] = rowptr[bhi];                                               \
    }                                                                       \
    int b0 = 0, b1 = 0;                                                     \
    if (i < n) { b0 = rowptr[i]; b1 = rowptr[i + 1]; }                      \
    __syncthreads();                                                        \
    int eb0 = sb2[0];                                                       \
    int ecap = sb2[1] - eb0; if (ecap > ECAP2) ecap = ECAP2;                \
    for (int j = tid; j < ecap; j += TB) eL[j] = srcs[eb0 + j];             \
    __syncthreads();                                                        \
    if (i >= n) return;                                                     \
    int clo = b0 - eb0; if (clo > ecap) clo = ecap;                         \
    int chi = b1 - eb0; if (chi > ecap) chi = ecap;

// scalar gather: acc starts with self term
#define GATHER_F1(TBL, C0)                                                  \
    float C0##c1 = 0.f, C0##c2 = 0.f, C0##c3 = 0.f;                         \
    {                                                                       \
        int j = clo;                                                        \
        for (; j + 4 <= chi; j += 4) {                                      \
            int s0 = eL[j], s1v = eL[j+1], s2 = eL[j+2], s3 = eL[j+3];      \
            C0 += TBL[s0]; C0##c1 += TBL[s1v];                              \
            C0##c2 += TBL[s2]; C0##c3 += TBL[s3];                           \
        }                                                                   \
        for (; j < chi; ++j) C0 += TBL[eL[j]];                              \
        if (b1 - eb0 > ecap) {                                              \
            int st = (b0 - eb0 > ecap) ? b0 : eb0 + ecap;                   \
            for (int e = st; e < b1; ++e) C0 += TBL[srcs[e]];               \
        }                                                                   \
    }                                                                       \
    C0 = (C0 + C0##c1) + (C0##c2 + C0##c3);

__global__ __launch_bounds__(TB) void k_dinvprep(
    const int* __restrict__ rowptr, const float* __restrict__ x, int n,
    float4* __restrict__ xdt) {
    int i = blockIdx.x * blockDim.x + threadIdx.x;
    if (i >= n) return;
    float di = rsqrtf((float)(rowptr[i + 1] - rowptr[i] + 1));
    float4 xv = ((const float4*)x)[i];
    xdt[i] = make_float4(xv.x * di, xv.y * di, xv.z * di, xv.w * di);
}

__global__ __launch_bounds__(TB) void k_aggA1_s(
    const int* __restrict__ rowptr, const int* __restrict__ srcs,
    const float4* __restrict__ xdt, const float* __restrict__ gbuf, int n,
    float2* __restrict__ axy, float* __restrict__ s1t) {
    __shared__ int eL[ECAP2];
    __shared__ int sb2[2];
    SLAB_HEAD();
    float4 self = xdt[i];
    float a0x = self.x, a0y = self.y, a0z = self.z, a0w = self.w;
    float a1x = 0, a1y = 0, a1z = 0, a1w = 0;
    float a2x = 0, a2y = 0, a2z = 0, a2w = 0;
    float a3x = 0, a3y = 0, a3z = 0, a3w = 0;
    {
        int j = clo;
        for (; j + 4 <= chi; j += 4) {
            float4 v0 = xdt[eL[j]], v1 = xdt[eL[j+1]], v2 = xdt[eL[j+2]], v3 = xdt[eL[j+3]];
            a0x += v0.x; a0y += v0.y; a0z += v0.z; a0w += v0.w;
            a1x += v1.x; a1y += v1.y; a1z += v1.z; a1w += v1.w;
            a2x += v2.x; a2y += v2.y; a2z += v2.z; a2w += v2.w;
            a3x += v3.x; a3y += v3.y; a3z += v3.z; a3w += v3.w;
        }
        for (; j < chi; ++j) {
            float4 v0 = xdt[eL[j]];
            a0x += v0.x; a0y += v0.y; a0z += v0.z; a0w += v0.w;
        }
        if (b1 - eb0 > ecap) {
            int st = (b0 - eb0 > ecap) ? b0 : eb0 + ecap;
            for (int e = st; e < b1; ++e) {
                float4 v0 = xdt[srcs[e]];
                a0x += v0.x; a0y += v0.y; a0z += v0.z; a0w += v0.w;
            }
        }
    }
    float di = rsqrtf((float)(b1 - b0 + 1));
    float ax = ((a0x + a1x) + (a2x + a3x)) * di;
    float ay = ((a0y + a1y) + (a2y + a3y)) * di;
    float az = ((a0z + a1z) + (a2z + a3z)) * di;
    float aw = ((a0w + a1w) + (a2w + a3w)) * di;
    axy[i] = make_float2(ax, ay);
    float s1 = ax * gbuf[0] + ay * gbuf[1] + az * gbuf[2] + aw * gbuf[3] + gbuf[4];
    s1t[i] = s1 * di;
}

__global__ __launch_bounds__(TB) void k_aggR_s(
    const int* __restrict__ rowptr, const int* __restrict__ srcs,
    const float* __restrict__ s1t, const float2* __restrict__ axy,
    const float* __restrict__ Wr, const float* __restrict__ br, int n,
    float* __restrict__ rt) {
    __shared__ int eL[ECAP2];
    __shared__ int sb2[2];
    SLAB_HEAD();
    float c0 = s1t[i];
    GATHER_F1(s1t, c0);
    float di = rsqrtf((float)(b1 - b0 + 1));
    float Ps1 = c0 * di;
    float2 a = axy[i];
    float r = a.x * Wr[0] + a.y * Wr[1] + Ps1 + br[0];
    rt[i] = r * di;
}

__global__ __launch_bounds__(TB) void k_aggPr_s(
    const int* __restrict__ rowptr, const int* __restrict__ srcs,
    const float* __restrict__ rt, const float2* __restrict__ axy,
    const float* __restrict__ Wq, const float* __restrict__ bq, int n,
    float4* __restrict__ nd, float* __restrict__ v0t) {
    __shared__ int eL[ECAP2];
    __shared__ int sb2[2];
    __shared__ float wq[5 * LQ];
    if (threadIdx.x < 4 * LQ) wq[threadIdx.x] = Wq[threadIdx.x];
    else if (threadIdx.x < 5 * LQ) wq[threadIdx.x] = bq[threadIdx.x - 4 * LQ];
    SLAB_HEAD();
    float c0 = rt[i];
    GATHER_F1(rt, c0);
    float di = rsqrtf((float)(b1 - b0 + 1));
    float pr = c0 * di;
    float2 a = axy[i];
    nd[i] = make_float4(a.x, a.y, pr, di);
    float m = -1e30f;
    #pragma unroll
    for (int jj = 0; jj < LQ; jj++) {
        float q = fmaf(a.x, wq[jj], fmaf(a.y, wq[LQ + jj],
                  fmaf(pr, wq[2 * LQ + jj], wq[4 * LQ + jj])));
        m = fmaxf(m, q);
    }
    v0t[i] = m * di;
}

__global__ __launch_bounds__(TB) void k_iter_s(
    const int* __restrict__ rowptr, const int* __restrict__ srcs,
    const float* __restrict__ vdin, const float4* __restrict__ nd,
    const float* __restrict__ Wq, const float* __restrict__ bq, int n,
    float* __restrict__ vdout) {
    __shared__ int eL[ECAP2];
    __shared__ int sb2[2];
    __shared__ float wq[5 * LQ];
    if (threadIdx.x < 4 * LQ) wq[threadIdx.x] = Wq[threadIdx.x];
    else if (threadIdx.x < 5 * LQ) wq[threadIdx.x] = bq[threadIdx.x - 4 * LQ];
    SLAB_HEAD();
    float c0 = vdin[i];
    GATHER_F1(vdin, c0);
    float4 c = nd[i];
    float pv = c0 * c.w;
    float m = -1e30f;
    #pragma unroll
    for (int jj = 0; jj < LQ; jj++) {
        float q = fmaf(c.x, wq[jj], fmaf(c.y, wq[LQ + jj],
                  fmaf(c.z, wq[2 * LQ + jj], fmaf(pv, wq[3 * LQ + jj], wq[4 * LQ + jj]))));
        m = fmaxf(m, q);
    }
    vdout[i] = m * c.w;
}

__global__ __launch_bounds__(TB) void k_final_s(
    const int* __restrict__ rowptr, const int* __restrict__ srcs,
    const float* __restrict__ vdin, const float4* __restrict__ nd,
    const float* __restrict__ Wq, const float* __restrict__ bq,
    const float* __restrict__ Wpi, int n, float4* __restrict__ tdt) {
    __shared__ int eL[ECAP2];
    __shared__ int sb2[2];
    __shared__ float wq[5 * LQ];
    __shared__ float wps[4 * LQ];
    if (threadIdx.x < 4 * LQ) wq[threadIdx.x] = Wq[threadIdx.x];
    else if (threadIdx.x < 5 * LQ) wq[threadIdx.x] = bq[threadIdx.x - 4 * LQ];
    if (threadIdx.x < 4 * LQ) wps[threadIdx.x] = Wpi[8 + threadIdx.x];
    SLAB_HEAD();
    float c0 = vdin[i];
    GATHER_F1(vdin, c0);
    float4 c = nd[i];
    float pv = c0 * c.w;
    float t0 = 0.f, t1 = 0.f, t2 = 0.f, t3 = 0.f;
    #pragma unroll
    for (int jj = 0; jj < LQ; jj++) {
        float q = fmaf(c.x, wq[jj], fmaf(c.y, wq[LQ + jj],
                  fmaf(c.z, wq[2 * LQ + jj], fmaf(pv, wq[3 * LQ + jj], wq[4 * LQ + jj]))));
        t0 = fmaf(q, wps[jj * 4 + 0], t0);
        t1 = fmaf(q, wps[jj * 4 + 1], t1);
        t2 = fmaf(q, wps[jj * 4 + 2], t2);
        t3 = fmaf(q, wps[jj * 4 + 3], t3);
    }
    tdt[i] = make_float4(t0 * c.w, t1 * c.w, t2 * c.w, t3 * c.w);
}

__global__ __launch_bounds__(TB) void k_logits_s(
    const int* __restrict__ rowptr, const int* __restrict__ srcs,
    const float4* __restrict__ tdt, const float4* __restrict__ nd,
    const float* __restrict__ Wpi, const float* __restrict__ bpi, int n,
    float* __restrict__ out) {
    __shared__ int eL[ECAP2];
    __shared__ int sb2[2];
    SLAB_HEAD();
    float4 self = tdt[i];
    float a0x = self.x, a0y = self.y, a0z = self.z, a0w = self.w;
    float a1x = 0, a1y = 0, a1z = 0, a1w = 0;
    float a2x = 0, a2y = 0, a2z = 0, a2w = 0;
    float a3x = 0, a3y = 0, a3z = 0, a3w = 0;
    {
        int j = clo;
        for (; j + 4 <= chi; j += 4) {
            float4 v0 = tdt[eL[j]], v1 = tdt[eL[j+1]], v2 = tdt[eL[j+2]], v3 = tdt[eL[j+3]];
            a0x += v0.x; a0y += v0.y; a0z += v0.z; a0w += v0.w;
            a1x += v1.x; a1y += v1.y; a1z += v1.z; a1w += v1.w;
            a2x += v2.x; a2y += v2.y; a2z += v2.z; a2w += v2.w;
            a3x += v3.x; a3y += v3.y; a3z += v3.z; a3w += v3.w;
        }
        for (; j < chi; ++j) {
            float4 v0 = tdt[eL[j]];
            a0x += v0.x; a0y += v0.y; a0z += v0.z; a0w += v0.w;
        }
        if (b1 - eb0 > ecap) {
            int st = (b0 - eb0 > ecap) ? b0 : eb0 + ecap;
            for (int e = st; e < b1; ++e) {
                float4 v0 = tdt[srcs[e]];
                a0x += v0.x; a0y += v0.y; a0z += v0.z; a0w += v0.w;
            }
        }
    }
    float4 c = nd[i];
    float di = c.w;
    float l0 = c.x * Wpi[0] + c.y * Wpi[4] + ((a0x + a1x) + (a2x + a3x)) * di + bpi[0];
    float l1 = c.x * Wpi[1] + c.y * Wpi[5] + ((a0y + a1y) + (a2y + a3y)) * di + bpi[1];
    float l2 = c.x * Wpi[2] + c.y * Wpi[6] + ((a0z + a1z) + (a2z + a3z)) * di + bpi[2];
    float l3 = c.x * Wpi[3] + c.y * Wpi[7] + ((a0w + a1w) + (a2w + a3w)) * di + bpi[3];
    float mx = fmaxf(fmaxf(l0, l1), fmaxf(l2, l3));
    float e0 = expf(l0 - mx), e1 = expf(l1 - mx), e2 = expf(l2 - mx), e3 = expf(l3 - mx);
    float inv = 1.0f / (e0 + e1 + e2 + e3);
    ((float4*)out)[i] = make_float4(l0, l1, l2, l3);
    ((float4*)(out + (size_t)n * 4))[i] = make_float4(e0 * inv, e1 * inv, e2 * inv, e3 * inv);
}

extern "C" void kernel_launch(void* const* d_in, const int* in_sizes, int n_in,
                              void* d_out, int out_size, void* d_ws, size_t ws_size,
                              hipStream_t stream) {
    const float* x = (const float*)d_in[0];
    const int* ei = (const int*)d_in[1];   // int32: harness converts integer inputs
    const float* Wh = (const float*)d_in[2];
    const float* bh = (const float*)d_in[3];
    const float* Wr = (const float*)d_in[4];
    const float* br = (const float*)d_in[5];
    const float* Wq = (const float*)d_in[6];
    const float* bq = (const float*)d_in[7];
    const float* Wpi = (const float*)d_in[8];
    const float* bpi = (const float*)d_in[9];
    int n = in_sizes[0] / 4;
    int E = in_sizes[1] / 2;
    float* out = (float*)d_out;

    int SH = 0;
    while ((((n - 1) >> SH) + 1) > 256) SH++;
    int NB = ((n - 1) >> SH) + 1;
    int nblk2 = (E + P_CHUNK - 1) / P_CHUNK;
    bool fast = (SH <= 10) && (nblk2 <= 256) &&
                ((unsigned long long)n <= (1ull << (32 - SH)));

    char* w = (char*)d_ws;
    size_t off = 0;
    auto alloc = [&](size_t bytes) -> void* {
        void* p = w + off;
        off += (bytes + 255) & ~(size_t)255;
        return p;
    };

    int nblk1 = (n + SCAN_CHUNK - 1) / SCAN_CHUNK;
    int* rowptr = (int*)alloc((size_t)(n + 1) * 4);
    int* srcs = (int*)alloc((size_t)E * 4);
    unsigned* ebuf = (unsigned*)alloc((size_t)E * 4);
    int* cnt = (int*)alloc((size_t)n * 4);          // legacy path
    int* blksum = (int*)alloc((size_t)nblk1 * 4);   // legacy path
    int* btot = (int*)alloc(256 * 4);
    int* bbase = (int*)alloc(257 * 4);
    float* gbuf = (float*)alloc(8 * 4);
    int* offs = (int*)alloc((size_t)(fast ? nblk2 : 1) * 256 * 4);
    float4* xdt = (float4*)alloc((size_t)n * 16);
    float4* tdt = (float4*)alloc((size_t)n * 16);
    float* s1t = (float*)alloc((size_t)n * 4);
    float* rt = (float*)alloc((size_t)n * 4);
    float* v0t = (float*)alloc((size_t)n * 4);
    float* v1t = (float*)alloc((size_t)n * 4);
    float2* axy = (float2*)alloc((size_t)n * 8);
    float4* nd = (float4*)alloc((size_t)n * 16);
    int* head = (int*)alloc((size_t)n * 4);         // legacy path

    int gN = (n + TB - 1) / TB;
    int gE = (E + TB - 1) / TB;

    if (fast) {
        k_p1a<<<nblk2, PB, 0, stream>>>(ei + E, E, SH, offs, Wh, bh, Wr, gbuf);
        k_pscanA<<<256, 256, 0, stream>>>(offs, nblk2, btot);
        k_pscan2<<<1, 256, 0, stream>>>(btot, bbase, E);
        k_p1b<<<nblk2, PB, 0, stream>>>(ei, E, SH, offs, bbase, ebuf);
        k_p2a<<<NB, PB, 0, stream>>>(ebuf, bbase, SH, n, E, NB, rowptr);
        k_p2b<<<NB, PB, 0, stream>>>(ebuf, bbase, rowptr, SH, n, srcs);
    } else {
        hipMemsetAsync(cnt, 0, (size_t)n * 4, stream);
        k_hist<<<gE, TB, 0, stream>>>(ei, E, cnt);
        k_scan1<<<nblk1, TB, 0, stream>>>(cnt, n, rowptr, blksum);
        k_scan2<<<1, TB, 0, stream>>>(blksum, nblk1);
        k_scan3<<<gN, TB, 0, stream>>>(rowptr, blksum, n, E);
        k_headinit<<<gN, TB, 0, stream>>>(rowptr, n, head);
        k_scatter<<<gE, TB, 0, stream>>>(ei, E, head, srcs);
        k_wprep<<<1, TB, 0, stream>>>(Wh, bh, Wr, gbuf);
    }

    k_dinvprep<<<gN, TB, 0, stream>>>(rowptr, x, n, xdt);
    k_aggA1_s<<<gN, TB, 0, stream>>>(rowptr, srcs, xdt, gbuf, n, axy, s1t);
    k_aggR_s<<<gN, TB, 0, stream>>>(rowptr, srcs, s1t, axy, Wr, br, n, rt);
    k_aggPr_s<<<gN, TB, 0, stream>>>(rowptr, srcs, rt, axy, Wq, bq, n, nd, v0t);

    float* vin = v0t;
    float* vout = v1t;
    for (int it = 2; it <= 19; ++it) {
        k_iter_s<<<gN, TB, 0, stream>>>(rowptr, srcs, vin, nd, Wq, bq, n, vout);
        float* tmp = vin; vin = vout; vout = tmp;
    }
    k_final_s<<<gN, TB, 0, stream>>>(rowptr, srcs, vin, nd, Wq, bq, Wpi, n, tdt);
    k_logits_s<<<gN, TB, 0, stream>>>(rowptr, srcs, tdt, nd, Wpi, bpi, n, out);
}